// Round 5
// baseline (794.940 us; speedup 1.0000x reference)
//
#include <hip/hip_runtime.h>
#include <cstdint>
#include <cstddef>

// ---------------------------------------------------------------------------
// HeteroGNN round 13: 8-deep in-register gather, occupancy-preserving.
//   Scoreboard: r9 depth-4 @75% occ = 99.6us; r12 depth-8-LDS @38% occ =
//   107us (per-wave throughput ~2x but LDS cost halved occupancy). r10/r11:
//   compiler reorders (VGPR 28) or spills (launch_bounds(256,8) cap=64).
//   Fix: depth-8 WITHIN one iteration (acc_k depends on load_k -> no legal
//   cross-iter hoist), ONE sched_barrier(0) between the 8-load block and the
//   8-acc block, launch_bounds(256,6) -> VGPR cap 85 so RA allocates ~60-70
//   instead of spilling. No LDS. Tail = one masked 8-deep superiter with
//   zero-row redirect.
//   Witnesses: VGPR 56-72 + WRITE_SIZE 40MB (no spill) = schedule survived.
// Pipeline: fused bucket build -> fused counting sort -> sorted CSR ->
// 8-deep sub-wave gather agg -> MFMA GEMM (16x16x32_bf16, m89 layouts),
// layer-3 transform-first. fp32 accumulation throughout.
// ---------------------------------------------------------------------------

static __host__ __device__ inline int cdiv_i(int a, int b) { return (a + b - 1) / b; }

typedef __attribute__((ext_vector_type(8))) short bf16x8;
typedef __attribute__((ext_vector_type(4))) float f32x4;
typedef __attribute__((ext_vector_type(2))) float f32x2;

__device__ inline unsigned short f2bf(float f) {
  unsigned u = __float_as_uint(f);
  return (unsigned short)((u + 0x7fffu + ((u >> 16) & 1u)) >> 16);  // RNE
}
__device__ inline f32x2 bfpair(unsigned u) {
  f32x2 v;
  v.x = __uint_as_float(u << 16);
  v.y = __uint_as_float(u & 0xffff0000u);
  return v;
}
// paired accumulate: p[k] += {elem 2k, elem 2k+1}; hipcc emits v_pk_add_f32
__device__ inline void accp(f32x2* p, uint4 r) {
  p[0] += bfpair(r.x);
  p[1] += bfpair(r.y);
  p[2] += bfpair(r.z);
  p[3] += bfpair(r.w);
}
__device__ inline uint4 packp(const f32x2* p, float inv) {
  uint4 o;
  o.x = (unsigned)f2bf(p[0].x * inv) | ((unsigned)f2bf(p[0].y * inv) << 16);
  o.y = (unsigned)f2bf(p[1].x * inv) | ((unsigned)f2bf(p[1].y * inv) << 16);
  o.z = (unsigned)f2bf(p[2].x * inv) | ((unsigned)f2bf(p[2].y * inv) << 16);
  o.w = (unsigned)f2bf(p[3].x * inv) | ((unsigned)f2bf(p[3].y * inv) << 16);
  return o;
}

#define CHUNK 8192
#define MAXNB 391  // user relation: cdiv(100000, 256)

// ---------------- phase 1: fused bucketed edge build (r6, proven) ----------

__global__ __launch_bounds__(1024) void build_buckets_k(
    const int* __restrict__ src_r, const int* __restrict__ dst_r, int E_r, int nc_r, int nb_r,
    int shift_r, int cap_r, int* __restrict__ cnt_r, unsigned* __restrict__ out_r,
    const int* __restrict__ src_u, const int* __restrict__ dst_u, int E_u, int nc_u, int nb_u,
    int shift_u, int cap_u, int* __restrict__ cnt_u, unsigned* __restrict__ out_u,
    const int* __restrict__ src_s, const int* __restrict__ dst_s, int E_s, int nc_s, int nb_s,
    int shift_s, int cap_s, int* __restrict__ cnt_s, unsigned* __restrict__ out_s) {
  __shared__ int A[MAXNB];
  __shared__ int B[MAXNB];
  __shared__ int w4[4];
  __shared__ unsigned stage[CHUNK];
  __shared__ unsigned short bstage[CHUNK];

  int bid = blockIdx.x;
  const int* src;
  const int* dst;
  int E, nb, shift, cap, c0;
  int* cnt;
  unsigned* out;
  if (bid < nc_r) {
    src = src_r; dst = dst_r; E = E_r; nb = nb_r; shift = shift_r; cap = cap_r;
    cnt = cnt_r; out = out_r; c0 = bid;
  } else if (bid < nc_r + nc_u) {
    src = src_u; dst = dst_u; E = E_u; nb = nb_u; shift = shift_u; cap = cap_u;
    cnt = cnt_u; out = out_u; c0 = bid - nc_r;
  } else {
    src = src_s; dst = dst_s; E = E_s; nb = nb_s; shift = shift_s; cap = cap_s;
    cnt = cnt_s; out = out_s; c0 = bid - nc_r - nc_u;
  }
  int mask = (1 << shift) - 1;
  int tid = threadIdx.x;
  int e0 = c0 * CHUNK;
  int chunk_n = min(CHUNK, E - e0);

  for (int i = tid; i < nb; i += 1024) A[i] = 0;
  __syncthreads();
  for (int t = tid; t < chunk_n; t += 1024) atomicAdd(&A[dst[e0 + t] >> shift], 1);
  __syncthreads();

  int s = 0, x = 0;
  int lane = tid & 63, wv = tid >> 6;
  int stride = (nb + 255) >> 8;
  int lo = 0, hi = 0;
  if (tid < 256) {
    lo = tid * stride;
    hi = min(lo + stride, nb);
    for (int i = lo; i < hi; ++i) s += A[i];
    x = s;
#pragma unroll
    for (int off = 1; off < 64; off <<= 1) {
      int y = __shfl_up(x, off, 64);
      if (lane >= off) x += y;
    }
    if (lane == 63) w4[wv] = x;
  }
  __syncthreads();
  if (tid < 256) {
    int woff = 0;
    for (int k = 0; k < wv; ++k) woff += w4[k];
    int run = woff + x - s;
    for (int i = lo; i < hi; ++i) {
      B[i] = run;
      run += A[i];
    }
  }
  __syncthreads();

  for (int b = tid; b < nb; b += 1024) {
    int h = A[b];
    if (h > 0) {
      int g = atomicAdd(&cnt[b], h);
      A[b] = g + b * cap - B[b];
    }
  }
  __syncthreads();

  for (int t = tid; t < chunk_n; t += 1024) {
    int e = e0 + t;
    int d = dst[e];
    int b = d >> shift;
    int p = atomicAdd(&B[b], 1);
    stage[p] = ((unsigned)src[e] << shift) | (unsigned)(d & mask);
    bstage[p] = (unsigned short)b;
  }
  __syncthreads();

  for (int p = tid; p < chunk_n; p += 1024) {
    int b = (int)bstage[p];
    out[(size_t)(A[b] + p)] = stage[p];
  }
}

// ---------------- phase 2: fused per-bucket counting sort (r6, proven) ------

__global__ __launch_bounds__(512) void sort_bucket_k(
    unsigned* __restrict__ bkt_r, const int* __restrict__ cnt_r, int nb_r, int shift_r,
    int cap_r, int* __restrict__ beg_r, int* __restrict__ end_r, int nd_r,
    unsigned* __restrict__ bkt_u, const int* __restrict__ cnt_u, int nb_u, int shift_u,
    int cap_u, int* __restrict__ beg_u, int* __restrict__ end_u, int nd_u,
    unsigned* __restrict__ bkt_s, const int* __restrict__ cnt_s, int nb_s, int shift_s,
    int cap_s, int* __restrict__ beg_s, int* __restrict__ end_s, int nd_s) {
  __shared__ int bins[256];
  __shared__ int w4[4];
  extern __shared__ int stage[];

  int bid = blockIdx.x;
  unsigned* bkt;
  const int* cnt;
  int shift, cap, ndst, b;
  int* beg;
  int* end;
  if (bid < nb_r) {
    bkt = bkt_r; cnt = cnt_r; shift = shift_r; cap = cap_r; beg = beg_r; end = end_r;
    ndst = nd_r; b = bid;
  } else if (bid < nb_r + nb_u) {
    bkt = bkt_u; cnt = cnt_u; shift = shift_u; cap = cap_u; beg = beg_u; end = end_u;
    ndst = nd_u; b = bid - nb_r;
  } else {
    bkt = bkt_s; cnt = cnt_s; shift = shift_s; cap = cap_s; beg = beg_s; end = end_s;
    ndst = nd_s; b = bid - nb_r - nb_u;
  }
  int g = 1 << shift;
  unsigned mask = (unsigned)(g - 1);
  int tid = threadIdx.x;
  int n = cnt[b];
  unsigned* eb = bkt + (size_t)b * cap;

  for (int i = tid; i < 256; i += 512) bins[i] = 0;
  __syncthreads();
  for (int t = tid; t < n; t += 512) atomicAdd(&bins[eb[t] & mask], 1);
  __syncthreads();

  int v = 0, x = 0;
  int lane = tid & 63, wv = tid >> 6;
  if (tid < 256) {
    v = (tid < g) ? bins[tid] : 0;
    x = v;
#pragma unroll
    for (int off = 1; off < 64; off <<= 1) {
      int y = __shfl_up(x, off, 64);
      if (lane >= off) x += y;
    }
    if (lane == 63) w4[wv] = x;
  }
  __syncthreads();
  if (tid < 256) {
    int woff = 0;
    for (int k = 0; k < wv; ++k) woff += w4[k];
    x += woff;
    int excl = x - v;
    if (tid < g) {
      int gnode = b * g + tid;
      if (gnode < ndst) {
        beg[gnode] = b * cap + excl;
        end[gnode] = b * cap + x;
      }
      bins[tid] = excl;
    }
  }
  __syncthreads();
  for (int t = tid; t < n; t += 512) {
    unsigned r = eb[t];
    int p = atomicAdd(&bins[r & mask], 1);
    stage[p] = (int)(r >> shift);
  }
  __syncthreads();
  for (int t = tid; t < n; t += 512) eb[t] = (unsigned)stage[t];
}

// ---------------- dtype conversion ----------------

__global__ void cvt_f32_bf16_k(const float* __restrict__ in, unsigned short* __restrict__ out,
                               int n4) {
  int i = blockIdx.x * blockDim.x + threadIdx.x;
  if (i >= n4) return;
  float4 v = ((const float4*)in)[i];
  uint2 u;
  u.x = (unsigned)f2bf(v.x) | ((unsigned)f2bf(v.y) << 16);
  u.y = (unsigned)f2bf(v.z) | ((unsigned)f2bf(v.w) << 16);
  ((uint2*)out)[i] = u;
}

// zero the appended gather rows (ws is re-poisoned before every launch)
__global__ void zero_rows_k(unsigned* p0, unsigned* p1, unsigned* p2, unsigned* p3,
                            unsigned* p4, unsigned* p5) {
  int t = threadIdx.x;  // 64 threads
  if (t < 32) p0[t] = 0;  // xu_bf zero row (32 uints)
  if (t < 32) p1[t] = 0;  // xi_bf
  if (t < 64) p2[t] = 0;  // hu_a (64 uints)
  if (t < 64) p3[t] = 0;  // hi_a
  if (t < 32) p4[t] = 0;  // yu0
  if (t < 64) p5[t] = 0;  // yi_st
}

// layers 0,1: fp32 [3][K][H] -> five bf16 [H][K] buffers
__global__ void cvt_layer_w_k(const float* __restrict__ Wl, const float* __restrict__ Wr, int K,
                              int H, unsigned short* __restrict__ wl_r,
                              unsigned short* __restrict__ wl_s,
                              unsigned short* __restrict__ wr_i,
                              unsigned short* __restrict__ wl_u,
                              unsigned short* __restrict__ wr_u) {
  int idx = blockIdx.x * blockDim.x + threadIdx.x;
  int kh = K * H;
  if (idx >= kh) return;
  int k = idx / H, h = idx - (idx / H) * H;
  int to = h * K + k;
  wl_r[to] = f2bf(0.5f * Wl[0 * kh + idx]);
  wl_s[to] = f2bf(0.5f * Wl[2 * kh + idx]);
  wr_i[to] = f2bf(0.5f * (Wr[0 * kh + idx] + Wr[2 * kh + idx]));
  wl_u[to] = f2bf(Wl[1 * kh + idx]);
  wr_u[to] = f2bf(Wr[1 * kh + idx]);
}

// layer 2 (final, K=128, H=64), transform-first weights
__global__ void cvt_final_w_k(const float* __restrict__ Wl, const float* __restrict__ Wr,
                              unsigned short* __restrict__ w_yu,
                              unsigned short* __restrict__ w_st,
                              unsigned short* __restrict__ wr_i,
                              unsigned short* __restrict__ wr_u) {
  int idx = blockIdx.x * blockDim.x + threadIdx.x;  // over K*H = 128*64
  if (idx >= 128 * 64) return;
  int k = idx / 64, h = idx - (idx / 64) * 64;
  int kh = 128 * 64;
  int src = k * 64 + h;
  w_yu[h * 128 + k] = f2bf(0.5f * Wl[0 * kh + src]);
  w_st[h * 128 + k] = f2bf(0.5f * Wl[2 * kh + src]);
  w_st[(h + 64) * 128 + k] = f2bf(Wl[1 * kh + src]);
  wr_i[h * 128 + k] = f2bf(0.5f * (Wr[0 * kh + src] + Wr[2 * kh + src]));
  wr_u[h * 128 + k] = f2bf(Wr[1 * kh + src]);
}

// ---------------- fused mean aggregation: 8-deep sub-wave walk --------------
// agg64: one OCTET per dst node (8 nodes/wave); agg128: one QUARTER per node.
// Per iteration: 8 idx loads + 8 row gathers, ONE sched_barrier(0), then 8
// packed-f32x2 accumulates. acc_k depends on load_k so the compiler cannot
// hoist accs above their loads; the single barrier stops it from splitting
// the batch (4+4) to save registers. launch_bounds(256,6) gives RA an 85-VGPR
// budget so the 8 in-flight uint4 allocate instead of spilling (r11 lesson).
// Tail = one masked 8-deep superiter (zero-row redirect).

__global__ __launch_bounds__(256, 6) void agg64_fused_k(
    const unsigned* __restrict__ x0, int st0, int of0, int zr0, const int* __restrict__ bg0,
    const int* __restrict__ en0, const unsigned* __restrict__ cl0, unsigned* __restrict__ m0,
    int nd0,
    const unsigned* __restrict__ x1, int st1, int of1, int zr1, const int* __restrict__ bg1,
    const int* __restrict__ en1, const unsigned* __restrict__ cl1, unsigned* __restrict__ m1,
    int nd1,
    const unsigned* __restrict__ x2, int st2, int of2, int zr2, const int* __restrict__ bg2,
    const int* __restrict__ en2, const unsigned* __restrict__ cl2, unsigned* __restrict__ m2,
    int nd2) {
  int node = blockIdx.x * 32 + (threadIdx.x >> 3);  // octet id = dst node
  int j = threadIdx.x & 7;                          // 16B chunk within 128B row
  const unsigned* xs;
  const int* bg;
  const int* en;
  const unsigned* cl;
  unsigned* mv;
  int st, ofs, zr, wv;
  if (node < nd0) {
    xs = x0; st = st0; ofs = of0; zr = zr0; bg = bg0; en = en0; cl = cl0; mv = m0; wv = node;
  } else if (node < nd0 + nd1) {
    xs = x1; st = st1; ofs = of1; zr = zr1; bg = bg1; en = en1; cl = cl1; mv = m1;
    wv = node - nd0;
  } else {
    wv = node - nd0 - nd1;
    if (wv >= nd2) return;
    xs = x2; st = st2; ofs = of2; zr = zr2; bg = bg2; en = en2; cl = cl2; mv = m2;
  }
  int b = bg[wv], ee = en[wv];
  f32x2 p[4] = {};
  int e = b;
  for (; e + 8 <= ee; e += 8) {
    int s0 = (int)cl[e + 0];
    int s1 = (int)cl[e + 1];
    int s2 = (int)cl[e + 2];
    int s3 = (int)cl[e + 3];
    int s4 = (int)cl[e + 4];
    int s5 = (int)cl[e + 5];
    int s6 = (int)cl[e + 6];
    int s7 = (int)cl[e + 7];
    uint4 r0 = ((const uint4*)(xs + (size_t)s0 * st + ofs))[j];
    uint4 r1 = ((const uint4*)(xs + (size_t)s1 * st + ofs))[j];
    uint4 r2 = ((const uint4*)(xs + (size_t)s2 * st + ofs))[j];
    uint4 r3 = ((const uint4*)(xs + (size_t)s3 * st + ofs))[j];
    uint4 r4 = ((const uint4*)(xs + (size_t)s4 * st + ofs))[j];
    uint4 r5 = ((const uint4*)(xs + (size_t)s5 * st + ofs))[j];
    uint4 r6 = ((const uint4*)(xs + (size_t)s6 * st + ofs))[j];
    uint4 r7 = ((const uint4*)(xs + (size_t)s7 * st + ofs))[j];
    __builtin_amdgcn_sched_barrier(0);  // keep all 8 loads issued before accs
    accp(p, r0);
    accp(p, r1);
    accp(p, r2);
    accp(p, r3);
    accp(p, r4);
    accp(p, r5);
    accp(p, r6);
    accp(p, r7);
  }
  if (e < ee) {
    int last = ee - 1;
    int s0 = (int)cl[e];
    int s1 = (int)cl[min(e + 1, last)];
    int s2 = (int)cl[min(e + 2, last)];
    int s3 = (int)cl[min(e + 3, last)];
    int s4 = (int)cl[min(e + 4, last)];
    int s5 = (int)cl[min(e + 5, last)];
    int s6 = (int)cl[min(e + 6, last)];
    int s7 = (int)cl[min(e + 7, last)];
    s1 = (e + 1 < ee) ? s1 : zr;
    s2 = (e + 2 < ee) ? s2 : zr;
    s3 = (e + 3 < ee) ? s3 : zr;
    s4 = (e + 4 < ee) ? s4 : zr;
    s5 = (e + 5 < ee) ? s5 : zr;
    s6 = (e + 6 < ee) ? s6 : zr;
    s7 = (e + 7 < ee) ? s7 : zr;
    uint4 r0 = ((const uint4*)(xs + (size_t)s0 * st + ofs))[j];
    uint4 r1 = ((const uint4*)(xs + (size_t)s1 * st + ofs))[j];
    uint4 r2 = ((const uint4*)(xs + (size_t)s2 * st + ofs))[j];
    uint4 r3 = ((const uint4*)(xs + (size_t)s3 * st + ofs))[j];
    uint4 r4 = ((const uint4*)(xs + (size_t)s4 * st + ofs))[j];
    uint4 r5 = ((const uint4*)(xs + (size_t)s5 * st + ofs))[j];
    uint4 r6 = ((const uint4*)(xs + (size_t)s6 * st + ofs))[j];
    uint4 r7 = ((const uint4*)(xs + (size_t)s7 * st + ofs))[j];
    __builtin_amdgcn_sched_barrier(0);
    accp(p, r0);
    accp(p, r1);
    accp(p, r2);
    accp(p, r3);
    accp(p, r4);
    accp(p, r5);
    accp(p, r6);
    accp(p, r7);
  }
  float inv = 1.f / (float)max(ee - b, 1);
  ((uint4*)(mv + (size_t)wv * 32))[j] = packp(p, inv);
}

__global__ __launch_bounds__(256, 6) void agg128_fused_k(
    const unsigned* __restrict__ x0, int zr0, const int* __restrict__ bg0,
    const int* __restrict__ en0, const unsigned* __restrict__ cl0, unsigned* __restrict__ m0,
    int nd0,
    const unsigned* __restrict__ x1, int zr1, const int* __restrict__ bg1,
    const int* __restrict__ en1, const unsigned* __restrict__ cl1, unsigned* __restrict__ m1,
    int nd1,
    const unsigned* __restrict__ x2, int zr2, const int* __restrict__ bg2,
    const int* __restrict__ en2, const unsigned* __restrict__ cl2, unsigned* __restrict__ m2,
    int nd2) {
  int node = blockIdx.x * 16 + (threadIdx.x >> 4);  // quarter id = dst node
  int j = threadIdx.x & 15;                         // 16B chunk within 256B row
  const unsigned* xs;
  const int* bg;
  const int* en;
  const unsigned* cl;
  unsigned* mv;
  int zr, wv;
  if (node < nd0) {
    xs = x0; zr = zr0; bg = bg0; en = en0; cl = cl0; mv = m0; wv = node;
  } else if (node < nd0 + nd1) {
    xs = x1; zr = zr1; bg = bg1; en = en1; cl = cl1; mv = m1; wv = node - nd0;
  } else {
    wv = node - nd0 - nd1;
    if (wv >= nd2) return;
    xs = x2; zr = zr2; bg = bg2; en = en2; cl = cl2; mv = m2;
  }
  int b = bg[wv], ee = en[wv];
  f32x2 p[4] = {};
  int e = b;
  for (; e + 8 <= ee; e += 8) {
    int s0 = (int)cl[e + 0];
    int s1 = (int)cl[e + 1];
    int s2 = (int)cl[e + 2];
    int s3 = (int)cl[e + 3];
    int s4 = (int)cl[e + 4];
    int s5 = (int)cl[e + 5];
    int s6 = (int)cl[e + 6];
    int s7 = (int)cl[e + 7];
    uint4 r0 = ((const uint4*)(xs + (size_t)s0 * 64))[j];
    uint4 r1 = ((const uint4*)(xs + (size_t)s1 * 64))[j];
    uint4 r2 = ((const uint4*)(xs + (size_t)s2 * 64))[j];
    uint4 r3 = ((const uint4*)(xs + (size_t)s3 * 64))[j];
    uint4 r4 = ((const uint4*)(xs + (size_t)s4 * 64))[j];
    uint4 r5 = ((const uint4*)(xs + (size_t)s5 * 64))[j];
    uint4 r6 = ((const uint4*)(xs + (size_t)s6 * 64))[j];
    uint4 r7 = ((const uint4*)(xs + (size_t)s7 * 64))[j];
    __builtin_amdgcn_sched_barrier(0);  // keep all 8 loads issued before accs
    accp(p, r0);
    accp(p, r1);
    accp(p, r2);
    accp(p, r3);
    accp(p, r4);
    accp(p, r5);
    accp(p, r6);
    accp(p, r7);
  }
  if (e < ee) {
    int last = ee - 1;
    int s0 = (int)cl[e];
    int s1 = (int)cl[min(e + 1, last)];
    int s2 = (int)cl[min(e + 2, last)];
    int s3 = (int)cl[min(e + 3, last)];
    int s4 = (int)cl[min(e + 4, last)];
    int s5 = (int)cl[min(e + 5, last)];
    int s6 = (int)cl[min(e + 6, last)];
    int s7 = (int)cl[min(e + 7, last)];
    s1 = (e + 1 < ee) ? s1 : zr;
    s2 = (e + 2 < ee) ? s2 : zr;
    s3 = (e + 3 < ee) ? s3 : zr;
    s4 = (e + 4 < ee) ? s4 : zr;
    s5 = (e + 5 < ee) ? s5 : zr;
    s6 = (e + 6 < ee) ? s6 : zr;
    s7 = (e + 7 < ee) ? s7 : zr;
    uint4 r0 = ((const uint4*)(xs + (size_t)s0 * 64))[j];
    uint4 r1 = ((const uint4*)(xs + (size_t)s1 * 64))[j];
    uint4 r2 = ((const uint4*)(xs + (size_t)s2 * 64))[j];
    uint4 r3 = ((const uint4*)(xs + (size_t)s3 * 64))[j];
    uint4 r4 = ((const uint4*)(xs + (size_t)s4 * 64))[j];
    uint4 r5 = ((const uint4*)(xs + (size_t)s5 * 64))[j];
    uint4 r6 = ((const uint4*)(xs + (size_t)s6 * 64))[j];
    uint4 r7 = ((const uint4*)(xs + (size_t)s7 * 64))[j];
    __builtin_amdgcn_sched_barrier(0);
    accp(p, r0);
    accp(p, r1);
    accp(p, r2);
    accp(p, r3);
    accp(p, r4);
    accp(p, r5);
    accp(p, r6);
    accp(p, r7);
  }
  float inv = 1.f / (float)max(ee - b, 1);
  ((uint4*)(mv + (size_t)wv * 64))[j] = packp(p, inv);
}

// ---------------- MFMA GEMM ----------------
// out = sum_ph A_ph@W_ph + bscale*(biasA[+biasB]) + add0 + add1; [relu]
// A: bf16 [n][K]; W: bf16 [H][K]; add0/1: bf16 [n][H]. fp32 acc.

__global__ __launch_bounds__(256) void gemm_mfma3_k(
    const unsigned short* __restrict__ A0, const unsigned short* __restrict__ W0,
    const unsigned short* __restrict__ A1, const unsigned short* __restrict__ W1,
    const unsigned short* __restrict__ A2, const unsigned short* __restrict__ W2,
    const float* __restrict__ biasA, const float* __restrict__ biasB, float bscale,
    const unsigned short* __restrict__ add0, const unsigned short* __restrict__ add1,
    float* __restrict__ out_f32, unsigned short* __restrict__ out_bf16, int n, int K, int H,
    int relu) {
  __shared__ alignas(16) unsigned short As[128 * 32];
  __shared__ alignas(16) unsigned short Bs[64 * 32];
  int tid = threadIdx.x;
  int row0 = blockIdx.x * 128;
  int col0 = blockIdx.y * 64;
  int w = tid >> 6, l = tid & 63;
  int lr = l & 15, lq = l >> 4;

  f32x4 acc[2][4] = {};
  int nph = A1 ? (A2 ? 3 : 2) : 1;

  for (int ph = 0; ph < nph; ++ph) {
    const unsigned short* Ap = (ph == 0) ? A0 : (ph == 1) ? A1 : A2;
    const unsigned short* Wp = (ph == 0) ? W0 : (ph == 1) ? W1 : W2;
    for (int k0 = 0; k0 < K; k0 += 32) {
      {
        int r = tid >> 2, cidx = tid & 3;
#pragma unroll
        for (int i = 0; i < 2; ++i) {
          int rr = r + i * 64;
          int gr = row0 + rr;
          uint4 v = make_uint4(0, 0, 0, 0);
          if (gr < n) v = *(const uint4*)(Ap + (size_t)gr * K + k0 + cidx * 8);
          *(uint4*)(As + rr * 32 + cidx * 8) = v;
        }
        int nn = tid >> 2;
        *(uint4*)(Bs + nn * 32 + cidx * 8) =
            *(const uint4*)(Wp + (size_t)(col0 + nn) * K + k0 + cidx * 8);
      }
      __syncthreads();
      bf16x8 af[2], bfr[4];
#pragma unroll
      for (int t = 0; t < 2; ++t)
        af[t] = *(const bf16x8*)(As + (w * 32 + t * 16 + lr) * 32 + lq * 8);
#pragma unroll
      for (int cidx = 0; cidx < 4; ++cidx)
        bfr[cidx] = *(const bf16x8*)(Bs + (cidx * 16 + lr) * 32 + lq * 8);
#pragma unroll
      for (int t = 0; t < 2; ++t)
#pragma unroll
        for (int cidx = 0; cidx < 4; ++cidx)
          acc[t][cidx] =
              __builtin_amdgcn_mfma_f32_16x16x32_bf16(af[t], bfr[cidx], acc[t][cidx], 0, 0, 0);
      __syncthreads();
    }
  }

#pragma unroll
  for (int t = 0; t < 2; ++t) {
#pragma unroll
    for (int cidx = 0; cidx < 4; ++cidx) {
      int gc = col0 + cidx * 16 + lr;
      float b = 0.f;
      if (biasA) b = biasA[gc];
      if (biasB) b += biasB[gc];
      b *= bscale;
#pragma unroll
      for (int r = 0; r < 4; ++r) {
        int gr = row0 + w * 32 + t * 16 + lq * 4 + r;
        if (gr >= n) continue;
        float val = acc[t][cidx][r] + b;
        size_t idx = (size_t)gr * H + gc;
        if (add0) val += __uint_as_float((unsigned)add0[idx] << 16);
        if (add1) val += __uint_as_float((unsigned)add1[idx] << 16);
        if (relu) val = fmaxf(val, 0.f);
        if (out_f32) out_f32[idx] = val;
        if (out_bf16) out_bf16[idx] = f2bf(val);
      }
    }
  }
}

// ---------------------------------------------------------------------------

extern "C" void kernel_launch(void* const* d_in, const int* in_sizes, int n_in, void* d_out,
                              int out_size, void* d_ws, size_t ws_size, hipStream_t stream) {
  const int NU = 100000, NI = 30000;
  const int O = 64;
  const int SH_I = 7, SH_U = 8;        // bucket = 128 dsts (items) / 256 (users)
  const int NB_R = cdiv_i(NI, 128);    // 235
  const int NB_U = cdiv_i(NU, 256);    // 391
  const int NB_S = cdiv_i(NI, 128);    // 235
  const int CAP_R = 7424, CAP_U = 4608, CAP_S = 2688;  // mu + ~12 sigma

  const float* x_user = (const float*)d_in[0];
  const float* x_item = (const float*)d_in[1];
  const int* e_rates = (const int*)d_in[2];
  const int* e_rated = (const int*)d_in[3];
  const int* e_sim = (const int*)d_in[4];
  const int ER = in_sizes[2] / 2;
  const int ERB = in_sizes[3] / 2;
  const int ES = in_sizes[4] / 2;
  const float* Wl0 = (const float*)d_in[5];
  const float* bl0 = (const float*)d_in[6];
  const float* Wr0 = (const float*)d_in[7];
  const float* Wl1 = (const float*)d_in[8];
  const float* bl1 = (const float*)d_in[9];
  const float* Wr1 = (const float*)d_in[10];
  const float* Wl2 = (const float*)d_in[11];
  const float* bl2 = (const float*)d_in[12];
  const float* Wr2 = (const float*)d_in[13];
  float* outp = (float*)d_out;

  // ---- workspace ----
  char* wsc = (char*)d_ws;
  size_t off = 0;
  auto alloc = [&](size_t bytes) -> char* {
    size_t cur = (off + 255) & ~(size_t)255;
    off = cur + bytes;
    return wsc + cur;
  };
  typedef unsigned short u16;
  int* cnt_all = (int*)alloc((size_t)(NB_R + NB_U + NB_S) * 4);
  int* cnt_r = cnt_all;
  int* cnt_u = cnt_r + NB_R;
  int* cnt_s = cnt_u + NB_U;
  unsigned* bkt_r = (unsigned*)alloc((size_t)NB_R * CAP_R * 4);
  unsigned* bkt_u = (unsigned*)alloc((size_t)NB_U * CAP_U * 4);
  unsigned* bkt_s = (unsigned*)alloc((size_t)NB_S * CAP_S * 4);
  int* beg_r = (int*)alloc((size_t)NI * 4);
  int* end_r = (int*)alloc((size_t)NI * 4);
  int* beg_u = (int*)alloc((size_t)NU * 4);
  int* end_u = (int*)alloc((size_t)NU * 4);
  int* beg_s = (int*)alloc((size_t)NI * 4);
  int* end_s = (int*)alloc((size_t)NI * 4);
  // gather tables get +1 zeroed row (index n) for masked tail lanes
  u16* xu_bf = (u16*)alloc((size_t)(NU + 1) * 64 * 2);
  u16* xi_bf = (u16*)alloc((size_t)(NI + 1) * 64 * 2);
  u16* mi_r = (u16*)alloc((size_t)NI * 64 * 2);
  u16* mi_s = (u16*)alloc((size_t)NI * 64 * 2);
  u16* mu3 = (u16*)alloc((size_t)NU * 64 * 2);
  u16* mean_ir = (u16*)alloc((size_t)NI * 128 * 2);
  u16* mean_is = (u16*)alloc((size_t)NI * 128 * 2);
  u16* mean_u = (u16*)alloc((size_t)NU * 128 * 2);
  u16* hu_a = (u16*)alloc((size_t)(NU + 1) * 128 * 2);
  u16* hu_b = (u16*)alloc((size_t)NU * 128 * 2);
  u16* hi_a = (u16*)alloc((size_t)(NI + 1) * 128 * 2);
  u16* hi_b = (u16*)alloc((size_t)NI * 128 * 2);
  u16* yu0 = (u16*)alloc((size_t)(NU + 1) * 64 * 2);
  u16* yi_st = (u16*)alloc((size_t)(NI + 1) * 128 * 2);
  u16* w0[5];
  for (int i = 0; i < 5; ++i) w0[i] = (u16*)alloc((size_t)64 * 128 * 2);
  u16* w1[5];
  for (int i = 0; i < 5; ++i) w1[i] = (u16*)alloc((size_t)128 * 128 * 2);
  u16* w2_yu = (u16*)alloc((size_t)64 * 128 * 2);
  u16* w2_st = (u16*)alloc((size_t)128 * 128 * 2);
  u16* wr_i2 = (u16*)alloc((size_t)64 * 128 * 2);
  u16* wr_u2 = (u16*)alloc((size_t)64 * 128 * 2);
  (void)ws_size;

  // ---- build + sort ----
  hipMemsetAsync(cnt_all, 0, (size_t)(NB_R + NB_U + NB_S) * 4, stream);
  int NC_R = cdiv_i(ER, CHUNK), NC_U = cdiv_i(ERB, CHUNK), NC_S = cdiv_i(ES, CHUNK);
  build_buckets_k<<<NC_R + NC_U + NC_S, 1024, 0, stream>>>(
      e_rates, e_rates + ER, ER, NC_R, NB_R, SH_I, CAP_R, cnt_r, bkt_r,
      e_rated, e_rated + ERB, ERB, NC_U, NB_U, SH_U, CAP_U, cnt_u, bkt_u,
      e_sim, e_sim + ES, ES, NC_S, NB_S, SH_I, CAP_S, cnt_s, bkt_s);
  sort_bucket_k<<<NB_R + NB_U + NB_S, 512, (size_t)CAP_R * 4, stream>>>(
      bkt_r, cnt_r, NB_R, SH_I, CAP_R, beg_r, end_r, NI,
      bkt_u, cnt_u, NB_U, SH_U, CAP_U, beg_u, end_u, NU,
      bkt_s, cnt_s, NB_S, SH_I, CAP_S, beg_s, end_s, NI);

  // ---- conversions + zero rows ----
  cvt_f32_bf16_k<<<cdiv_i(NU * 64 / 4, 256), 256, 0, stream>>>(x_user, xu_bf, NU * 64 / 4);
  cvt_f32_bf16_k<<<cdiv_i(NI * 64 / 4, 256), 256, 0, stream>>>(x_item, xi_bf, NI * 64 / 4);
  zero_rows_k<<<1, 64, 0, stream>>>(
      (unsigned*)(xu_bf + (size_t)NU * 64), (unsigned*)(xi_bf + (size_t)NI * 64),
      (unsigned*)(hu_a + (size_t)NU * 128), (unsigned*)(hi_a + (size_t)NI * 128),
      (unsigned*)(yu0 + (size_t)NU * 64), (unsigned*)(yi_st + (size_t)NI * 128));
  cvt_layer_w_k<<<cdiv_i(64 * 128, 256), 256, 0, stream>>>(Wl0, Wr0, 64, 128, w0[0], w0[1],
                                                           w0[2], w0[3], w0[4]);
  cvt_layer_w_k<<<cdiv_i(128 * 128, 256), 256, 0, stream>>>(Wl1, Wr1, 128, 128, w1[0], w1[1],
                                                            w1[2], w1[3], w1[4]);
  cvt_final_w_k<<<cdiv_i(128 * 64, 256), 256, 0, stream>>>(Wl2, Wr2, w2_yu, w2_st, wr_i2,
                                                           wr_u2);

  // ---- layer 1 (K=64 -> H=128) ----
  {
    agg64_fused_k<<<cdiv_i(NI + NI + NU, 32), 256, 0, stream>>>(
        (const unsigned*)xu_bf, 32, 0, NU, beg_r, end_r, bkt_r, (unsigned*)mi_r, NI,
        (const unsigned*)xi_bf, 32, 0, NI, beg_s, end_s, bkt_s, (unsigned*)mi_s, NI,
        (const unsigned*)xi_bf, 32, 0, NI, beg_u, end_u, bkt_u, (unsigned*)mu3, NU);
    dim3 gi(cdiv_i(NI, 128), 2), gu(cdiv_i(NU, 128), 2);
    gemm_mfma3_k<<<gi, 256, 0, stream>>>(mi_r, w0[0], mi_s, w0[1], xi_bf, w0[2], bl0 + 0 * 128,
                                         bl0 + 2 * 128, 0.5f, nullptr, nullptr, nullptr, hi_a,
                                         NI, 64, 128, 1);
    gemm_mfma3_k<<<gu, 256, 0, stream>>>(mu3, w0[3], xu_bf, w0[4], nullptr, nullptr,
                                         bl0 + 1 * 128, nullptr, 1.0f, nullptr, nullptr,
                                         nullptr, hu_a, NU, 64, 128, 1);
  }
  // ---- layer 2 (K=128 -> H=128) ----
  {
    agg128_fused_k<<<cdiv_i(NI + NI + NU, 16), 256, 0, stream>>>(
        (const unsigned*)hu_a, NU, beg_r, end_r, bkt_r, (unsigned*)mean_ir, NI,
        (const unsigned*)hi_a, NI, beg_s, end_s, bkt_s, (unsigned*)mean_is, NI,
        (const unsigned*)hi_a, NI, beg_u, end_u, bkt_u, (unsigned*)mean_u, NU);
    dim3 gi(cdiv_i(NI, 128), 2), gu(cdiv_i(NU, 128), 2);
    gemm_mfma3_k<<<gi, 256, 0, stream>>>(mean_ir, w1[0], mean_is, w1[1], hi_a, w1[2],
                                         bl1 + 0 * 128, bl1 + 2 * 128, 0.5f, nullptr, nullptr,
                                         nullptr, hi_b, NI, 128, 128, 1);
    gemm_mfma3_k<<<gu, 256, 0, stream>>>(mean_u, w1[3], hu_a, w1[4], nullptr, nullptr,
                                         bl1 + 1 * 128, nullptr, 1.0f, nullptr, nullptr,
                                         nullptr, hu_b, NU, 128, 128, 1);
  }
  // ---- layer 3 (K=128 -> O=64), transform-first ----
  {
    dim3 gp1(cdiv_i(NU, 128), 1), gp2(cdiv_i(NI, 128), 2);
    gemm_mfma3_k<<<gp1, 256, 0, stream>>>(hu_b, w2_yu, nullptr, nullptr, nullptr, nullptr,
                                          nullptr, nullptr, 0.f, nullptr, nullptr, nullptr,
                                          yu0, NU, 128, 64, 0);
    gemm_mfma3_k<<<gp2, 256, 0, stream>>>(hi_b, w2_st, nullptr, nullptr, nullptr, nullptr,
                                          nullptr, nullptr, 0.f, nullptr, nullptr, nullptr,
                                          yi_st, NI, 128, 128, 0);
    agg64_fused_k<<<cdiv_i(NI + NI + NU, 32), 256, 0, stream>>>(
        (const unsigned*)yu0, 32, 0, NU, beg_r, end_r, bkt_r, (unsigned*)mi_r, NI,
        (const unsigned*)yi_st, 64, 0, NI, beg_s, end_s, bkt_s, (unsigned*)mi_s, NI,
        (const unsigned*)yi_st, 64, 32, NI, beg_u, end_u, bkt_u, (unsigned*)mu3, NU);
    dim3 gi(cdiv_i(NI, 128), 1), gu(cdiv_i(NU, 128), 1);
    gemm_mfma3_k<<<gi, 256, 0, stream>>>(hi_b, wr_i2, nullptr, nullptr, nullptr, nullptr,
                                         bl2 + 0 * 64, bl2 + 2 * 64, 0.5f, mi_r, mi_s,
                                         outp + (size_t)NU * O, nullptr, NI, 128, 64, 0);
    gemm_mfma3_k<<<gu, 256, 0, stream>>>(hu_b, wr_u2, nullptr, nullptr, nullptr, nullptr,
                                         bl2 + 1 * 64, nullptr, 1.0f, mu3, nullptr, outp,
                                         nullptr, NU, 128, 64, 0);
  }
}

// Round 6
// 541.684 us; speedup vs baseline: 1.4675x; 1.4675x over previous
//
#include <hip/hip_runtime.h>
#include <cstdint>
#include <cstddef>

// ---------------------------------------------------------------------------
// HeteroGNN round 14: dword-per-lane wave-per-node gather (scalar-base).
//   r10/r11/r13 proved hipcc won't hold uint4 gather payloads in VGPRs
//   (reorder / spill / bigger spill); r12's LDS depth paid with occupancy.
//   Root fix: shrink payload-per-lane 4x. 256B row = 64 lanes x 1 dword ->
//   ONE WAVE per 128-dim node, per edge ONE global_load_dword (1 VGPR).
//   Depth-16 pipeline = 16 VGPRs. Row base is wave-uniform -> readfirstlane
//   puts address math in SGPRs with loop-invariant voffset=lane*4. acc =
//   single f32x2 (v_pk_add_f32), store = 1 coalesced dword/lane, no reduce.
//   agg64: half-wave per node (128B = 32 lanes x dword), per-lane 64b addr.
//   Tail: one 16-deep zero-row-redirect superiter.
//   Witnesses: WRITE 40MB (no spill), VGPR ~24-36, BW -> 5-6 TB/s.
// Pipeline: fused bucket build -> fused counting sort -> sorted CSR ->
// dword-gather agg -> MFMA GEMM (16x16x32_bf16, m89 layouts),
// layer-3 transform-first. fp32 accumulation throughout.
// ---------------------------------------------------------------------------

static __host__ __device__ inline int cdiv_i(int a, int b) { return (a + b - 1) / b; }

typedef __attribute__((ext_vector_type(8))) short bf16x8;
typedef __attribute__((ext_vector_type(4))) float f32x4;
typedef __attribute__((ext_vector_type(2))) float f32x2;

__device__ inline unsigned short f2bf(float f) {
  unsigned u = __float_as_uint(f);
  return (unsigned short)((u + 0x7fffu + ((u >> 16) & 1u)) >> 16);  // RNE
}
__device__ inline f32x2 bfpair(unsigned u) {
  f32x2 v;
  v.x = __uint_as_float(u << 16);
  v.y = __uint_as_float(u & 0xffff0000u);
  return v;
}

#define CHUNK 8192
#define MAXNB 391  // user relation: cdiv(100000, 256)

// ---------------- phase 1: fused bucketed edge build (r6, proven) ----------

__global__ __launch_bounds__(1024) void build_buckets_k(
    const int* __restrict__ src_r, const int* __restrict__ dst_r, int E_r, int nc_r, int nb_r,
    int shift_r, int cap_r, int* __restrict__ cnt_r, unsigned* __restrict__ out_r,
    const int* __restrict__ src_u, const int* __restrict__ dst_u, int E_u, int nc_u, int nb_u,
    int shift_u, int cap_u, int* __restrict__ cnt_u, unsigned* __restrict__ out_u,
    const int* __restrict__ src_s, const int* __restrict__ dst_s, int E_s, int nc_s, int nb_s,
    int shift_s, int cap_s, int* __restrict__ cnt_s, unsigned* __restrict__ out_s) {
  __shared__ int A[MAXNB];
  __shared__ int B[MAXNB];
  __shared__ int w4[4];
  __shared__ unsigned stage[CHUNK];
  __shared__ unsigned short bstage[CHUNK];

  int bid = blockIdx.x;
  const int* src;
  const int* dst;
  int E, nb, shift, cap, c0;
  int* cnt;
  unsigned* out;
  if (bid < nc_r) {
    src = src_r; dst = dst_r; E = E_r; nb = nb_r; shift = shift_r; cap = cap_r;
    cnt = cnt_r; out = out_r; c0 = bid;
  } else if (bid < nc_r + nc_u) {
    src = src_u; dst = dst_u; E = E_u; nb = nb_u; shift = shift_u; cap = cap_u;
    cnt = cnt_u; out = out_u; c0 = bid - nc_r;
  } else {
    src = src_s; dst = dst_s; E = E_s; nb = nb_s; shift = shift_s; cap = cap_s;
    cnt = cnt_s; out = out_s; c0 = bid - nc_r - nc_u;
  }
  int mask = (1 << shift) - 1;
  int tid = threadIdx.x;
  int e0 = c0 * CHUNK;
  int chunk_n = min(CHUNK, E - e0);

  for (int i = tid; i < nb; i += 1024) A[i] = 0;
  __syncthreads();
  for (int t = tid; t < chunk_n; t += 1024) atomicAdd(&A[dst[e0 + t] >> shift], 1);
  __syncthreads();

  int s = 0, x = 0;
  int lane = tid & 63, wv = tid >> 6;
  int stride = (nb + 255) >> 8;
  int lo = 0, hi = 0;
  if (tid < 256) {
    lo = tid * stride;
    hi = min(lo + stride, nb);
    for (int i = lo; i < hi; ++i) s += A[i];
    x = s;
#pragma unroll
    for (int off = 1; off < 64; off <<= 1) {
      int y = __shfl_up(x, off, 64);
      if (lane >= off) x += y;
    }
    if (lane == 63) w4[wv] = x;
  }
  __syncthreads();
  if (tid < 256) {
    int woff = 0;
    for (int k = 0; k < wv; ++k) woff += w4[k];
    int run = woff + x - s;
    for (int i = lo; i < hi; ++i) {
      B[i] = run;
      run += A[i];
    }
  }
  __syncthreads();

  for (int b = tid; b < nb; b += 1024) {
    int h = A[b];
    if (h > 0) {
      int g = atomicAdd(&cnt[b], h);
      A[b] = g + b * cap - B[b];
    }
  }
  __syncthreads();

  for (int t = tid; t < chunk_n; t += 1024) {
    int e = e0 + t;
    int d = dst[e];
    int b = d >> shift;
    int p = atomicAdd(&B[b], 1);
    stage[p] = ((unsigned)src[e] << shift) | (unsigned)(d & mask);
    bstage[p] = (unsigned short)b;
  }
  __syncthreads();

  for (int p = tid; p < chunk_n; p += 1024) {
    int b = (int)bstage[p];
    out[(size_t)(A[b] + p)] = stage[p];
  }
}

// ---------------- phase 2: fused per-bucket counting sort (r6, proven) ------

__global__ __launch_bounds__(512) void sort_bucket_k(
    unsigned* __restrict__ bkt_r, const int* __restrict__ cnt_r, int nb_r, int shift_r,
    int cap_r, int* __restrict__ beg_r, int* __restrict__ end_r, int nd_r,
    unsigned* __restrict__ bkt_u, const int* __restrict__ cnt_u, int nb_u, int shift_u,
    int cap_u, int* __restrict__ beg_u, int* __restrict__ end_u, int nd_u,
    unsigned* __restrict__ bkt_s, const int* __restrict__ cnt_s, int nb_s, int shift_s,
    int cap_s, int* __restrict__ beg_s, int* __restrict__ end_s, int nd_s) {
  __shared__ int bins[256];
  __shared__ int w4[4];
  extern __shared__ int stage[];

  int bid = blockIdx.x;
  unsigned* bkt;
  const int* cnt;
  int shift, cap, ndst, b;
  int* beg;
  int* end;
  if (bid < nb_r) {
    bkt = bkt_r; cnt = cnt_r; shift = shift_r; cap = cap_r; beg = beg_r; end = end_r;
    ndst = nd_r; b = bid;
  } else if (bid < nb_r + nb_u) {
    bkt = bkt_u; cnt = cnt_u; shift = shift_u; cap = cap_u; beg = beg_u; end = end_u;
    ndst = nd_u; b = bid - nb_r;
  } else {
    bkt = bkt_s; cnt = cnt_s; shift = shift_s; cap = cap_s; beg = beg_s; end = end_s;
    ndst = nd_s; b = bid - nb_r - nb_u;
  }
  int g = 1 << shift;
  unsigned mask = (unsigned)(g - 1);
  int tid = threadIdx.x;
  int n = cnt[b];
  unsigned* eb = bkt + (size_t)b * cap;

  for (int i = tid; i < 256; i += 512) bins[i] = 0;
  __syncthreads();
  for (int t = tid; t < n; t += 512) atomicAdd(&bins[eb[t] & mask], 1);
  __syncthreads();

  int v = 0, x = 0;
  int lane = tid & 63, wv = tid >> 6;
  if (tid < 256) {
    v = (tid < g) ? bins[tid] : 0;
    x = v;
#pragma unroll
    for (int off = 1; off < 64; off <<= 1) {
      int y = __shfl_up(x, off, 64);
      if (lane >= off) x += y;
    }
    if (lane == 63) w4[wv] = x;
  }
  __syncthreads();
  if (tid < 256) {
    int woff = 0;
    for (int k = 0; k < wv; ++k) woff += w4[k];
    x += woff;
    int excl = x - v;
    if (tid < g) {
      int gnode = b * g + tid;
      if (gnode < ndst) {
        beg[gnode] = b * cap + excl;
        end[gnode] = b * cap + x;
      }
      bins[tid] = excl;
    }
  }
  __syncthreads();
  for (int t = tid; t < n; t += 512) {
    unsigned r = eb[t];
    int p = atomicAdd(&bins[r & mask], 1);
    stage[p] = (int)(r >> shift);
  }
  __syncthreads();
  for (int t = tid; t < n; t += 512) eb[t] = (unsigned)stage[t];
}

// ---------------- dtype conversion ----------------

__global__ void cvt_f32_bf16_k(const float* __restrict__ in, unsigned short* __restrict__ out,
                               int n4) {
  int i = blockIdx.x * blockDim.x + threadIdx.x;
  if (i >= n4) return;
  float4 v = ((const float4*)in)[i];
  uint2 u;
  u.x = (unsigned)f2bf(v.x) | ((unsigned)f2bf(v.y) << 16);
  u.y = (unsigned)f2bf(v.z) | ((unsigned)f2bf(v.w) << 16);
  ((uint2*)out)[i] = u;
}

// zero the appended gather rows (ws is re-poisoned before every launch)
__global__ void zero_rows_k(unsigned* p0, unsigned* p1, unsigned* p2, unsigned* p3,
                            unsigned* p4, unsigned* p5) {
  int t = threadIdx.x;  // 64 threads
  if (t < 32) p0[t] = 0;  // xu_bf zero row (32 uints)
  if (t < 32) p1[t] = 0;  // xi_bf
  if (t < 64) p2[t] = 0;  // hu_a (64 uints)
  if (t < 64) p3[t] = 0;  // hi_a
  if (t < 32) p4[t] = 0;  // yu0
  if (t < 64) p5[t] = 0;  // yi_st
}

// layers 0,1: fp32 [3][K][H] -> five bf16 [H][K] buffers
__global__ void cvt_layer_w_k(const float* __restrict__ Wl, const float* __restrict__ Wr, int K,
                              int H, unsigned short* __restrict__ wl_r,
                              unsigned short* __restrict__ wl_s,
                              unsigned short* __restrict__ wr_i,
                              unsigned short* __restrict__ wl_u,
                              unsigned short* __restrict__ wr_u) {
  int idx = blockIdx.x * blockDim.x + threadIdx.x;
  int kh = K * H;
  if (idx >= kh) return;
  int k = idx / H, h = idx - (idx / H) * H;
  int to = h * K + k;
  wl_r[to] = f2bf(0.5f * Wl[0 * kh + idx]);
  wl_s[to] = f2bf(0.5f * Wl[2 * kh + idx]);
  wr_i[to] = f2bf(0.5f * (Wr[0 * kh + idx] + Wr[2 * kh + idx]));
  wl_u[to] = f2bf(Wl[1 * kh + idx]);
  wr_u[to] = f2bf(Wr[1 * kh + idx]);
}

// layer 2 (final, K=128, H=64), transform-first weights
__global__ void cvt_final_w_k(const float* __restrict__ Wl, const float* __restrict__ Wr,
                              unsigned short* __restrict__ w_yu,
                              unsigned short* __restrict__ w_st,
                              unsigned short* __restrict__ wr_i,
                              unsigned short* __restrict__ wr_u) {
  int idx = blockIdx.x * blockDim.x + threadIdx.x;  // over K*H = 128*64
  if (idx >= 128 * 64) return;
  int k = idx / 64, h = idx - (idx / 64) * 64;
  int kh = 128 * 64;
  int src = k * 64 + h;
  w_yu[h * 128 + k] = f2bf(0.5f * Wl[0 * kh + src]);
  w_st[h * 128 + k] = f2bf(0.5f * Wl[2 * kh + src]);
  w_st[(h + 64) * 128 + k] = f2bf(Wl[1 * kh + src]);
  wr_i[h * 128 + k] = f2bf(0.5f * (Wr[0 * kh + src] + Wr[2 * kh + src]));
  wr_u[h * 128 + k] = f2bf(Wr[1 * kh + src]);
}

// ---------------- fused mean aggregation: dword-per-lane gather -------------
// agg128: ONE WAVE per dst node; lane owns dword `lane` of the 256B row.
//   Row base is wave-uniform -> readfirstlane -> SGPR address math, shared
//   voffset. Per edge: 1 global_load_dword (1 VGPR payload) -> depth-16
//   pipeline costs 16 VGPRs. acc = f32x2; store = 1 coalesced dword/lane.
// agg64: HALF-WAVE per node (2 nodes/wave); lane owns dword (lane&31) of the
//   128B row; per-lane 64-bit addressing (base differs per half). Depth-16.
// Tail: one masked 16-deep superiter, invalid slots redirect to zero row.

__global__ __launch_bounds__(256) void agg64_fused_k(
    const unsigned* __restrict__ x0, int sh0, int of0, int zr0, const int* __restrict__ bg0,
    const int* __restrict__ en0, const unsigned* __restrict__ cl0, unsigned* __restrict__ m0,
    int nd0,
    const unsigned* __restrict__ x1, int sh1, int of1, int zr1, const int* __restrict__ bg1,
    const int* __restrict__ en1, const unsigned* __restrict__ cl1, unsigned* __restrict__ m1,
    int nd1,
    const unsigned* __restrict__ x2, int sh2, int of2, int zr2, const int* __restrict__ bg2,
    const int* __restrict__ en2, const unsigned* __restrict__ cl2, unsigned* __restrict__ m2,
    int nd2) {
  int node = blockIdx.x * 8 + (threadIdx.x >> 5);  // half-wave per node
  int j = threadIdx.x & 31;                        // dword within 128B row
  const unsigned* xs;
  const int* bg;
  const int* en;
  const unsigned* cl;
  unsigned* mv;
  int sh, ofs, zr, wv;
  if (node < nd0) {
    xs = x0; sh = sh0; ofs = of0; zr = zr0; bg = bg0; en = en0; cl = cl0; mv = m0; wv = node;
  } else if (node < nd0 + nd1) {
    xs = x1; sh = sh1; ofs = of1; zr = zr1; bg = bg1; en = en1; cl = cl1; mv = m1;
    wv = node - nd0;
  } else {
    wv = node - nd0 - nd1;
    if (wv >= nd2) return;
    xs = x2; sh = sh2; ofs = of2; zr = zr2; bg = bg2; en = en2; cl = cl2; mv = m2;
  }
  int b = bg[wv], ee = en[wv];
  f32x2 p = {0.f, 0.f};
  int e = b;
  for (; e + 16 <= ee; e += 16) {
    unsigned d[16];
#pragma unroll
    for (int k = 0; k < 16; ++k) {
      int s = (int)cl[e + k];
      d[k] = (xs + (((size_t)s) << sh) + ofs)[j];
    }
    __builtin_amdgcn_sched_barrier(0);  // keep the 16 loads batched above accs
#pragma unroll
    for (int k = 0; k < 16; ++k) p += bfpair(d[k]);
  }
  if (e < ee) {
    int last = ee - 1;
    unsigned d[16];
#pragma unroll
    for (int k = 0; k < 16; ++k) {
      int ek = e + k;
      int s = (int)cl[min(ek, last)];
      s = (ek < ee) ? s : zr;
      d[k] = (xs + (((size_t)s) << sh) + ofs)[j];
    }
    __builtin_amdgcn_sched_barrier(0);
#pragma unroll
    for (int k = 0; k < 16; ++k) p += bfpair(d[k]);
  }
  float inv = 1.f / (float)max(ee - b, 1);
  mv[(size_t)wv * 32 + j] = (unsigned)f2bf(p.x * inv) | ((unsigned)f2bf(p.y * inv) << 16);
}

__global__ __launch_bounds__(256) void agg128_fused_k(
    const unsigned* __restrict__ x0, int zr0, const int* __restrict__ bg0,
    const int* __restrict__ en0, const unsigned* __restrict__ cl0, unsigned* __restrict__ m0,
    int nd0,
    const unsigned* __restrict__ x1, int zr1, const int* __restrict__ bg1,
    const int* __restrict__ en1, const unsigned* __restrict__ cl1, unsigned* __restrict__ m1,
    int nd1,
    const unsigned* __restrict__ x2, int zr2, const int* __restrict__ bg2,
    const int* __restrict__ en2, const unsigned* __restrict__ cl2, unsigned* __restrict__ m2,
    int nd2) {
  int wave = threadIdx.x >> 6;
  int lane = threadIdx.x & 63;  // dword within 256B row
  int node = blockIdx.x * 4 + wave;  // one WAVE per dst node
  const unsigned* xs;
  const int* bg;
  const int* en;
  const unsigned* cl;
  unsigned* mv;
  int zr, wv;
  if (node < nd0) {
    xs = x0; zr = zr0; bg = bg0; en = en0; cl = cl0; mv = m0; wv = node;
  } else if (node < nd0 + nd1) {
    xs = x1; zr = zr1; bg = bg1; en = en1; cl = cl1; mv = m1; wv = node - nd0;
  } else {
    wv = node - nd0 - nd1;
    if (wv >= nd2) return;  // whole wave exits together
    xs = x2; zr = zr2; bg = bg2; en = en2; cl = cl2; mv = m2;
  }
  int b = bg[wv], ee = en[wv];  // wave-uniform
  f32x2 p = {0.f, 0.f};
  int e = b;
  for (; e + 16 <= ee; e += 16) {
    unsigned d[16];
#pragma unroll
    for (int k = 0; k < 16; ++k) {
      // cl[e+k] is wave-uniform; readfirstlane -> SGPR base, shared voffset
      unsigned sb = (unsigned)__builtin_amdgcn_readfirstlane((int)cl[e + k]);
      d[k] = (xs + (size_t)sb * 64)[lane];
    }
    __builtin_amdgcn_sched_barrier(0);  // keep the 16 loads batched above accs
#pragma unroll
    for (int k = 0; k < 16; ++k) p += bfpair(d[k]);
  }
  if (e < ee) {
    int last = ee - 1;
    unsigned d[16];
#pragma unroll
    for (int k = 0; k < 16; ++k) {
      int ek = e + k;
      int s = (int)cl[min(ek, last)];
      s = (ek < ee) ? s : zr;
      unsigned sb = (unsigned)__builtin_amdgcn_readfirstlane(s);
      d[k] = (xs + (size_t)sb * 64)[lane];
    }
    __builtin_amdgcn_sched_barrier(0);
#pragma unroll
    for (int k = 0; k < 16; ++k) p += bfpair(d[k]);
  }
  float inv = 1.f / (float)max(ee - b, 1);
  mv[(size_t)wv * 64 + lane] = (unsigned)f2bf(p.x * inv) | ((unsigned)f2bf(p.y * inv) << 16);
}

// ---------------- MFMA GEMM ----------------
// out = sum_ph A_ph@W_ph + bscale*(biasA[+biasB]) + add0 + add1; [relu]
// A: bf16 [n][K]; W: bf16 [H][K]; add0/1: bf16 [n][H]. fp32 acc.

__global__ __launch_bounds__(256) void gemm_mfma3_k(
    const unsigned short* __restrict__ A0, const unsigned short* __restrict__ W0,
    const unsigned short* __restrict__ A1, const unsigned short* __restrict__ W1,
    const unsigned short* __restrict__ A2, const unsigned short* __restrict__ W2,
    const float* __restrict__ biasA, const float* __restrict__ biasB, float bscale,
    const unsigned short* __restrict__ add0, const unsigned short* __restrict__ add1,
    float* __restrict__ out_f32, unsigned short* __restrict__ out_bf16, int n, int K, int H,
    int relu) {
  __shared__ alignas(16) unsigned short As[128 * 32];
  __shared__ alignas(16) unsigned short Bs[64 * 32];
  int tid = threadIdx.x;
  int row0 = blockIdx.x * 128;
  int col0 = blockIdx.y * 64;
  int w = tid >> 6, l = tid & 63;
  int lr = l & 15, lq = l >> 4;

  f32x4 acc[2][4] = {};
  int nph = A1 ? (A2 ? 3 : 2) : 1;

  for (int ph = 0; ph < nph; ++ph) {
    const unsigned short* Ap = (ph == 0) ? A0 : (ph == 1) ? A1 : A2;
    const unsigned short* Wp = (ph == 0) ? W0 : (ph == 1) ? W1 : W2;
    for (int k0 = 0; k0 < K; k0 += 32) {
      {
        int r = tid >> 2, cidx = tid & 3;
#pragma unroll
        for (int i = 0; i < 2; ++i) {
          int rr = r + i * 64;
          int gr = row0 + rr;
          uint4 v = make_uint4(0, 0, 0, 0);
          if (gr < n) v = *(const uint4*)(Ap + (size_t)gr * K + k0 + cidx * 8);
          *(uint4*)(As + rr * 32 + cidx * 8) = v;
        }
        int nn = tid >> 2;
        *(uint4*)(Bs + nn * 32 + cidx * 8) =
            *(const uint4*)(Wp + (size_t)(col0 + nn) * K + k0 + cidx * 8);
      }
      __syncthreads();
      bf16x8 af[2], bfr[4];
#pragma unroll
      for (int t = 0; t < 2; ++t)
        af[t] = *(const bf16x8*)(As + (w * 32 + t * 16 + lr) * 32 + lq * 8);
#pragma unroll
      for (int cidx = 0; cidx < 4; ++cidx)
        bfr[cidx] = *(const bf16x8*)(Bs + (cidx * 16 + lr) * 32 + lq * 8);
#pragma unroll
      for (int t = 0; t < 2; ++t)
#pragma unroll
        for (int cidx = 0; cidx < 4; ++cidx)
          acc[t][cidx] =
              __builtin_amdgcn_mfma_f32_16x16x32_bf16(af[t], bfr[cidx], acc[t][cidx], 0, 0, 0);
      __syncthreads();
    }
  }

#pragma unroll
  for (int t = 0; t < 2; ++t) {
#pragma unroll
    for (int cidx = 0; cidx < 4; ++cidx) {
      int gc = col0 + cidx * 16 + lr;
      float b = 0.f;
      if (biasA) b = biasA[gc];
      if (biasB) b += biasB[gc];
      b *= bscale;
#pragma unroll
      for (int r = 0; r < 4; ++r) {
        int gr = row0 + w * 32 + t * 16 + lq * 4 + r;
        if (gr >= n) continue;
        float val = acc[t][cidx][r] + b;
        size_t idx = (size_t)gr * H + gc;
        if (add0) val += __uint_as_float((unsigned)add0[idx] << 16);
        if (add1) val += __uint_as_float((unsigned)add1[idx] << 16);
        if (relu) val = fmaxf(val, 0.f);
        if (out_f32) out_f32[idx] = val;
        if (out_bf16) out_bf16[idx] = f2bf(val);
      }
    }
  }
}

// ---------------------------------------------------------------------------

extern "C" void kernel_launch(void* const* d_in, const int* in_sizes, int n_in, void* d_out,
                              int out_size, void* d_ws, size_t ws_size, hipStream_t stream) {
  const int NU = 100000, NI = 30000;
  const int O = 64;
  const int SH_I = 7, SH_U = 8;        // bucket = 128 dsts (items) / 256 (users)
  const int NB_R = cdiv_i(NI, 128);    // 235
  const int NB_U = cdiv_i(NU, 256);    // 391
  const int NB_S = cdiv_i(NI, 128);    // 235
  const int CAP_R = 7424, CAP_U = 4608, CAP_S = 2688;  // mu + ~12 sigma

  const float* x_user = (const float*)d_in[0];
  const float* x_item = (const float*)d_in[1];
  const int* e_rates = (const int*)d_in[2];
  const int* e_rated = (const int*)d_in[3];
  const int* e_sim = (const int*)d_in[4];
  const int ER = in_sizes[2] / 2;
  const int ERB = in_sizes[3] / 2;
  const int ES = in_sizes[4] / 2;
  const float* Wl0 = (const float*)d_in[5];
  const float* bl0 = (const float*)d_in[6];
  const float* Wr0 = (const float*)d_in[7];
  const float* Wl1 = (const float*)d_in[8];
  const float* bl1 = (const float*)d_in[9];
  const float* Wr1 = (const float*)d_in[10];
  const float* Wl2 = (const float*)d_in[11];
  const float* bl2 = (const float*)d_in[12];
  const float* Wr2 = (const float*)d_in[13];
  float* outp = (float*)d_out;

  // ---- workspace ----
  char* wsc = (char*)d_ws;
  size_t off = 0;
  auto alloc = [&](size_t bytes) -> char* {
    size_t cur = (off + 255) & ~(size_t)255;
    off = cur + bytes;
    return wsc + cur;
  };
  typedef unsigned short u16;
  int* cnt_all = (int*)alloc((size_t)(NB_R + NB_U + NB_S) * 4);
  int* cnt_r = cnt_all;
  int* cnt_u = cnt_r + NB_R;
  int* cnt_s = cnt_u + NB_U;
  unsigned* bkt_r = (unsigned*)alloc((size_t)NB_R * CAP_R * 4);
  unsigned* bkt_u = (unsigned*)alloc((size_t)NB_U * CAP_U * 4);
  unsigned* bkt_s = (unsigned*)alloc((size_t)NB_S * CAP_S * 4);
  int* beg_r = (int*)alloc((size_t)NI * 4);
  int* end_r = (int*)alloc((size_t)NI * 4);
  int* beg_u = (int*)alloc((size_t)NU * 4);
  int* end_u = (int*)alloc((size_t)NU * 4);
  int* beg_s = (int*)alloc((size_t)NI * 4);
  int* end_s = (int*)alloc((size_t)NI * 4);
  // gather tables get +1 zeroed row (index n) for masked tail lanes
  u16* xu_bf = (u16*)alloc((size_t)(NU + 1) * 64 * 2);
  u16* xi_bf = (u16*)alloc((size_t)(NI + 1) * 64 * 2);
  u16* mi_r = (u16*)alloc((size_t)NI * 64 * 2);
  u16* mi_s = (u16*)alloc((size_t)NI * 64 * 2);
  u16* mu3 = (u16*)alloc((size_t)NU * 64 * 2);
  u16* mean_ir = (u16*)alloc((size_t)NI * 128 * 2);
  u16* mean_is = (u16*)alloc((size_t)NI * 128 * 2);
  u16* mean_u = (u16*)alloc((size_t)NU * 128 * 2);
  u16* hu_a = (u16*)alloc((size_t)(NU + 1) * 128 * 2);
  u16* hu_b = (u16*)alloc((size_t)NU * 128 * 2);
  u16* hi_a = (u16*)alloc((size_t)(NI + 1) * 128 * 2);
  u16* hi_b = (u16*)alloc((size_t)NI * 128 * 2);
  u16* yu0 = (u16*)alloc((size_t)(NU + 1) * 64 * 2);
  u16* yi_st = (u16*)alloc((size_t)(NI + 1) * 128 * 2);
  u16* w0[5];
  for (int i = 0; i < 5; ++i) w0[i] = (u16*)alloc((size_t)64 * 128 * 2);
  u16* w1[5];
  for (int i = 0; i < 5; ++i) w1[i] = (u16*)alloc((size_t)128 * 128 * 2);
  u16* w2_yu = (u16*)alloc((size_t)64 * 128 * 2);
  u16* w2_st = (u16*)alloc((size_t)128 * 128 * 2);
  u16* wr_i2 = (u16*)alloc((size_t)64 * 128 * 2);
  u16* wr_u2 = (u16*)alloc((size_t)64 * 128 * 2);
  (void)ws_size;

  // ---- build + sort ----
  hipMemsetAsync(cnt_all, 0, (size_t)(NB_R + NB_U + NB_S) * 4, stream);
  int NC_R = cdiv_i(ER, CHUNK), NC_U = cdiv_i(ERB, CHUNK), NC_S = cdiv_i(ES, CHUNK);
  build_buckets_k<<<NC_R + NC_U + NC_S, 1024, 0, stream>>>(
      e_rates, e_rates + ER, ER, NC_R, NB_R, SH_I, CAP_R, cnt_r, bkt_r,
      e_rated, e_rated + ERB, ERB, NC_U, NB_U, SH_U, CAP_U, cnt_u, bkt_u,
      e_sim, e_sim + ES, ES, NC_S, NB_S, SH_I, CAP_S, cnt_s, bkt_s);
  sort_bucket_k<<<NB_R + NB_U + NB_S, 512, (size_t)CAP_R * 4, stream>>>(
      bkt_r, cnt_r, NB_R, SH_I, CAP_R, beg_r, end_r, NI,
      bkt_u, cnt_u, NB_U, SH_U, CAP_U, beg_u, end_u, NU,
      bkt_s, cnt_s, NB_S, SH_I, CAP_S, beg_s, end_s, NI);

  // ---- conversions + zero rows ----
  cvt_f32_bf16_k<<<cdiv_i(NU * 64 / 4, 256), 256, 0, stream>>>(x_user, xu_bf, NU * 64 / 4);
  cvt_f32_bf16_k<<<cdiv_i(NI * 64 / 4, 256), 256, 0, stream>>>(x_item, xi_bf, NI * 64 / 4);
  zero_rows_k<<<1, 64, 0, stream>>>(
      (unsigned*)(xu_bf + (size_t)NU * 64), (unsigned*)(xi_bf + (size_t)NI * 64),
      (unsigned*)(hu_a + (size_t)NU * 128), (unsigned*)(hi_a + (size_t)NI * 128),
      (unsigned*)(yu0 + (size_t)NU * 64), (unsigned*)(yi_st + (size_t)NI * 128));
  cvt_layer_w_k<<<cdiv_i(64 * 128, 256), 256, 0, stream>>>(Wl0, Wr0, 64, 128, w0[0], w0[1],
                                                           w0[2], w0[3], w0[4]);
  cvt_layer_w_k<<<cdiv_i(128 * 128, 256), 256, 0, stream>>>(Wl1, Wr1, 128, 128, w1[0], w1[1],
                                                            w1[2], w1[3], w1[4]);
  cvt_final_w_k<<<cdiv_i(128 * 64, 256), 256, 0, stream>>>(Wl2, Wr2, w2_yu, w2_st, wr_i2,
                                                           wr_u2);

  // ---- layer 1 (K=64 -> H=128) ----
  {
    agg64_fused_k<<<cdiv_i(NI + NI + NU, 8), 256, 0, stream>>>(
        (const unsigned*)xu_bf, 5, 0, NU, beg_r, end_r, bkt_r, (unsigned*)mi_r, NI,
        (const unsigned*)xi_bf, 5, 0, NI, beg_s, end_s, bkt_s, (unsigned*)mi_s, NI,
        (const unsigned*)xi_bf, 5, 0, NI, beg_u, end_u, bkt_u, (unsigned*)mu3, NU);
    dim3 gi(cdiv_i(NI, 128), 2), gu(cdiv_i(NU, 128), 2);
    gemm_mfma3_k<<<gi, 256, 0, stream>>>(mi_r, w0[0], mi_s, w0[1], xi_bf, w0[2], bl0 + 0 * 128,
                                         bl0 + 2 * 128, 0.5f, nullptr, nullptr, nullptr, hi_a,
                                         NI, 64, 128, 1);
    gemm_mfma3_k<<<gu, 256, 0, stream>>>(mu3, w0[3], xu_bf, w0[4], nullptr, nullptr,
                                         bl0 + 1 * 128, nullptr, 1.0f, nullptr, nullptr,
                                         nullptr, hu_a, NU, 64, 128, 1);
  }
  // ---- layer 2 (K=128 -> H=128) ----
  {
    agg128_fused_k<<<cdiv_i(NI + NI + NU, 4), 256, 0, stream>>>(
        (const unsigned*)hu_a, NU, beg_r, end_r, bkt_r, (unsigned*)mean_ir, NI,
        (const unsigned*)hi_a, NI, beg_s, end_s, bkt_s, (unsigned*)mean_is, NI,
        (const unsigned*)hi_a, NI, beg_u, end_u, bkt_u, (unsigned*)mean_u, NU);
    dim3 gi(cdiv_i(NI, 128), 2), gu(cdiv_i(NU, 128), 2);
    gemm_mfma3_k<<<gi, 256, 0, stream>>>(mean_ir, w1[0], mean_is, w1[1], hi_a, w1[2],
                                         bl1 + 0 * 128, bl1 + 2 * 128, 0.5f, nullptr, nullptr,
                                         nullptr, hi_b, NI, 128, 128, 1);
    gemm_mfma3_k<<<gu, 256, 0, stream>>>(mean_u, w1[3], hu_a, w1[4], nullptr, nullptr,
                                         bl1 + 1 * 128, nullptr, 1.0f, nullptr, nullptr,
                                         nullptr, hu_b, NU, 128, 128, 1);
  }
  // ---- layer 3 (K=128 -> O=64), transform-first ----
  {
    dim3 gp1(cdiv_i(NU, 128), 1), gp2(cdiv_i(NI, 128), 2);
    gemm_mfma3_k<<<gp1, 256, 0, stream>>>(hu_b, w2_yu, nullptr, nullptr, nullptr, nullptr,
                                          nullptr, nullptr, 0.f, nullptr, nullptr, nullptr,
                                          yu0, NU, 128, 64, 0);
    gemm_mfma3_k<<<gp2, 256, 0, stream>>>(hi_b, w2_st, nullptr, nullptr, nullptr, nullptr,
                                          nullptr, nullptr, 0.f, nullptr, nullptr, nullptr,
                                          yi_st, NI, 128, 128, 0);
    agg64_fused_k<<<cdiv_i(NI + NI + NU, 8), 256, 0, stream>>>(
        (const unsigned*)yu0, 5, 0, NU, beg_r, end_r, bkt_r, (unsigned*)mi_r, NI,
        (const unsigned*)yi_st, 6, 0, NI, beg_s, end_s, bkt_s, (unsigned*)mi_s, NI,
        (const unsigned*)yi_st, 6, 32, NI, beg_u, end_u, bkt_u, (unsigned*)mu3, NU);
    dim3 gi(cdiv_i(NI, 128), 1), gu(cdiv_i(NU, 128), 1);
    gemm_mfma3_k<<<gi, 256, 0, stream>>>(hi_b, wr_i2, nullptr, nullptr, nullptr, nullptr,
                                         bl2 + 0 * 64, bl2 + 2 * 64, 0.5f, mi_r, mi_s,
                                         outp + (size_t)NU * O, nullptr, NI, 128, 64, 0);
    gemm_mfma3_k<<<gu, 256, 0, stream>>>(hu_b, wr_u2, nullptr, nullptr, nullptr, nullptr,
                                         bl2 + 1 * 64, nullptr, 1.0f, mu3, nullptr, outp,
                                         nullptr, NU, 128, 64, 0);
  }
}

// Round 7
// 513.732 us; speedup vs baseline: 1.5474x; 1.0544x over previous
//
#include <hip/hip_runtime.h>
#include <cstdint>
#include <cstddef>

// ---------------------------------------------------------------------------
// HeteroGNN round 15: r9 agg (measured best) + global_load_lds GEMM staging.
//   agg: r9-r14 scoreboard - five structures (4-deep subwave / forced reg
//   pipeline / LDS-DMA / 8-deep / dword-per-lane) all land 99-112us with
//   demand-side ~8-9 TB/s and FETCH at the 311MB compulsory floor -> random
//   256B-gather subsystem ceiling. r9's sub-wave 4-deep form is the best
//   operating point (99.6us); reverted to it exactly.
//   GEMM: staging was a VGPR round-trip (Common-mistake #1). The thread map
//   (t -> LDS addr t*16B) is already linear, so swap in 3x global_load_lds
//   width-16 per wave per K-step (2 A + 1 B); same LDS layout (0 conflicts
//   measured); OOB rows clamped (pollute only skipped epilogue rows).
// Pipeline: fused bucket build -> fused counting sort -> sorted CSR ->
// sub-wave gather agg -> MFMA GEMM (16x16x32_bf16, m89 layouts),
// layer-3 transform-first. fp32 accumulation throughout.
// ---------------------------------------------------------------------------

static __host__ __device__ inline int cdiv_i(int a, int b) { return (a + b - 1) / b; }

typedef __attribute__((ext_vector_type(8))) short bf16x8;
typedef __attribute__((ext_vector_type(4))) float f32x4;

__device__ inline float bf_lo(unsigned u) { return __uint_as_float(u << 16); }
__device__ inline float bf_hi(unsigned u) { return __uint_as_float(u & 0xffff0000u); }
__device__ inline unsigned short f2bf(float f) {
  unsigned u = __float_as_uint(f);
  return (unsigned short)((u + 0x7fffu + ((u >> 16) & 1u)) >> 16);  // RNE
}
__device__ inline void acc8(float* a, uint4 r) {
  a[0] += bf_lo(r.x);
  a[1] += bf_hi(r.x);
  a[2] += bf_lo(r.y);
  a[3] += bf_hi(r.y);
  a[4] += bf_lo(r.z);
  a[5] += bf_hi(r.z);
  a[6] += bf_lo(r.w);
  a[7] += bf_hi(r.w);
}
__device__ inline uint4 pack8(const float* a, float inv) {
  uint4 o;
  o.x = (unsigned)f2bf(a[0] * inv) | ((unsigned)f2bf(a[1] * inv) << 16);
  o.y = (unsigned)f2bf(a[2] * inv) | ((unsigned)f2bf(a[3] * inv) << 16);
  o.z = (unsigned)f2bf(a[4] * inv) | ((unsigned)f2bf(a[5] * inv) << 16);
  o.w = (unsigned)f2bf(a[6] * inv) | ((unsigned)f2bf(a[7] * inv) << 16);
  return o;
}

// async 16B/lane global->LDS; lds dest = wave-uniform base + lane*16 (HW rule)
__device__ inline void dma16(const void* g, void* l) {
  __builtin_amdgcn_global_load_lds((const __attribute__((address_space(1))) void*)g,
                                   (__attribute__((address_space(3))) void*)l, 16, 0, 0);
}

#define CHUNK 8192
#define MAXNB 391  // user relation: cdiv(100000, 256)

// ---------------- phase 1: fused bucketed edge build (r6, proven) ----------

__global__ __launch_bounds__(1024) void build_buckets_k(
    const int* __restrict__ src_r, const int* __restrict__ dst_r, int E_r, int nc_r, int nb_r,
    int shift_r, int cap_r, int* __restrict__ cnt_r, unsigned* __restrict__ out_r,
    const int* __restrict__ src_u, const int* __restrict__ dst_u, int E_u, int nc_u, int nb_u,
    int shift_u, int cap_u, int* __restrict__ cnt_u, unsigned* __restrict__ out_u,
    const int* __restrict__ src_s, const int* __restrict__ dst_s, int E_s, int nc_s, int nb_s,
    int shift_s, int cap_s, int* __restrict__ cnt_s, unsigned* __restrict__ out_s) {
  __shared__ int A[MAXNB];
  __shared__ int B[MAXNB];
  __shared__ int w4[4];
  __shared__ unsigned stage[CHUNK];
  __shared__ unsigned short bstage[CHUNK];

  int bid = blockIdx.x;
  const int* src;
  const int* dst;
  int E, nb, shift, cap, c0;
  int* cnt;
  unsigned* out;
  if (bid < nc_r) {
    src = src_r; dst = dst_r; E = E_r; nb = nb_r; shift = shift_r; cap = cap_r;
    cnt = cnt_r; out = out_r; c0 = bid;
  } else if (bid < nc_r + nc_u) {
    src = src_u; dst = dst_u; E = E_u; nb = nb_u; shift = shift_u; cap = cap_u;
    cnt = cnt_u; out = out_u; c0 = bid - nc_r;
  } else {
    src = src_s; dst = dst_s; E = E_s; nb = nb_s; shift = shift_s; cap = cap_s;
    cnt = cnt_s; out = out_s; c0 = bid - nc_r - nc_u;
  }
  int mask = (1 << shift) - 1;
  int tid = threadIdx.x;
  int e0 = c0 * CHUNK;
  int chunk_n = min(CHUNK, E - e0);

  for (int i = tid; i < nb; i += 1024) A[i] = 0;
  __syncthreads();
  for (int t = tid; t < chunk_n; t += 1024) atomicAdd(&A[dst[e0 + t] >> shift], 1);
  __syncthreads();

  int s = 0, x = 0;
  int lane = tid & 63, wv = tid >> 6;
  int stride = (nb + 255) >> 8;
  int lo = 0, hi = 0;
  if (tid < 256) {
    lo = tid * stride;
    hi = min(lo + stride, nb);
    for (int i = lo; i < hi; ++i) s += A[i];
    x = s;
#pragma unroll
    for (int off = 1; off < 64; off <<= 1) {
      int y = __shfl_up(x, off, 64);
      if (lane >= off) x += y;
    }
    if (lane == 63) w4[wv] = x;
  }
  __syncthreads();
  if (tid < 256) {
    int woff = 0;
    for (int k = 0; k < wv; ++k) woff += w4[k];
    int run = woff + x - s;
    for (int i = lo; i < hi; ++i) {
      B[i] = run;
      run += A[i];
    }
  }
  __syncthreads();

  for (int b = tid; b < nb; b += 1024) {
    int h = A[b];
    if (h > 0) {
      int g = atomicAdd(&cnt[b], h);
      A[b] = g + b * cap - B[b];
    }
  }
  __syncthreads();

  for (int t = tid; t < chunk_n; t += 1024) {
    int e = e0 + t;
    int d = dst[e];
    int b = d >> shift;
    int p = atomicAdd(&B[b], 1);
    stage[p] = ((unsigned)src[e] << shift) | (unsigned)(d & mask);
    bstage[p] = (unsigned short)b;
  }
  __syncthreads();

  for (int p = tid; p < chunk_n; p += 1024) {
    int b = (int)bstage[p];
    out[(size_t)(A[b] + p)] = stage[p];
  }
}

// ---------------- phase 2: fused per-bucket counting sort (r6, proven) ------

__global__ __launch_bounds__(512) void sort_bucket_k(
    unsigned* __restrict__ bkt_r, const int* __restrict__ cnt_r, int nb_r, int shift_r,
    int cap_r, int* __restrict__ beg_r, int* __restrict__ end_r, int nd_r,
    unsigned* __restrict__ bkt_u, const int* __restrict__ cnt_u, int nb_u, int shift_u,
    int cap_u, int* __restrict__ beg_u, int* __restrict__ end_u, int nd_u,
    unsigned* __restrict__ bkt_s, const int* __restrict__ cnt_s, int nb_s, int shift_s,
    int cap_s, int* __restrict__ beg_s, int* __restrict__ end_s, int nd_s) {
  __shared__ int bins[256];
  __shared__ int w4[4];
  extern __shared__ int stage[];

  int bid = blockIdx.x;
  unsigned* bkt;
  const int* cnt;
  int shift, cap, ndst, b;
  int* beg;
  int* end;
  if (bid < nb_r) {
    bkt = bkt_r; cnt = cnt_r; shift = shift_r; cap = cap_r; beg = beg_r; end = end_r;
    ndst = nd_r; b = bid;
  } else if (bid < nb_r + nb_u) {
    bkt = bkt_u; cnt = cnt_u; shift = shift_u; cap = cap_u; beg = beg_u; end = end_u;
    ndst = nd_u; b = bid - nb_r;
  } else {
    bkt = bkt_s; cnt = cnt_s; shift = shift_s; cap = cap_s; beg = beg_s; end = end_s;
    ndst = nd_s; b = bid - nb_r - nb_u;
  }
  int g = 1 << shift;
  unsigned mask = (unsigned)(g - 1);
  int tid = threadIdx.x;
  int n = cnt[b];
  unsigned* eb = bkt + (size_t)b * cap;

  for (int i = tid; i < 256; i += 512) bins[i] = 0;
  __syncthreads();
  for (int t = tid; t < n; t += 512) atomicAdd(&bins[eb[t] & mask], 1);
  __syncthreads();

  int v = 0, x = 0;
  int lane = tid & 63, wv = tid >> 6;
  if (tid < 256) {
    v = (tid < g) ? bins[tid] : 0;
    x = v;
#pragma unroll
    for (int off = 1; off < 64; off <<= 1) {
      int y = __shfl_up(x, off, 64);
      if (lane >= off) x += y;
    }
    if (lane == 63) w4[wv] = x;
  }
  __syncthreads();
  if (tid < 256) {
    int woff = 0;
    for (int k = 0; k < wv; ++k) woff += w4[k];
    x += woff;
    int excl = x - v;
    if (tid < g) {
      int gnode = b * g + tid;
      if (gnode < ndst) {
        beg[gnode] = b * cap + excl;
        end[gnode] = b * cap + x;
      }
      bins[tid] = excl;
    }
  }
  __syncthreads();
  for (int t = tid; t < n; t += 512) {
    unsigned r = eb[t];
    int p = atomicAdd(&bins[r & mask], 1);
    stage[p] = (int)(r >> shift);
  }
  __syncthreads();
  for (int t = tid; t < n; t += 512) eb[t] = (unsigned)stage[t];
}

// ---------------- dtype conversion ----------------

__global__ void cvt_f32_bf16_k(const float* __restrict__ in, unsigned short* __restrict__ out,
                               int n4) {
  int i = blockIdx.x * blockDim.x + threadIdx.x;
  if (i >= n4) return;
  float4 v = ((const float4*)in)[i];
  uint2 u;
  u.x = (unsigned)f2bf(v.x) | ((unsigned)f2bf(v.y) << 16);
  u.y = (unsigned)f2bf(v.z) | ((unsigned)f2bf(v.w) << 16);
  ((uint2*)out)[i] = u;
}

// layers 0,1: fp32 [3][K][H] -> five bf16 [H][K] buffers
__global__ void cvt_layer_w_k(const float* __restrict__ Wl, const float* __restrict__ Wr, int K,
                              int H, unsigned short* __restrict__ wl_r,
                              unsigned short* __restrict__ wl_s,
                              unsigned short* __restrict__ wr_i,
                              unsigned short* __restrict__ wl_u,
                              unsigned short* __restrict__ wr_u) {
  int idx = blockIdx.x * blockDim.x + threadIdx.x;
  int kh = K * H;
  if (idx >= kh) return;
  int k = idx / H, h = idx - (idx / H) * H;
  int to = h * K + k;
  wl_r[to] = f2bf(0.5f * Wl[0 * kh + idx]);
  wl_s[to] = f2bf(0.5f * Wl[2 * kh + idx]);
  wr_i[to] = f2bf(0.5f * (Wr[0 * kh + idx] + Wr[2 * kh + idx]));
  wl_u[to] = f2bf(Wl[1 * kh + idx]);
  wr_u[to] = f2bf(Wr[1 * kh + idx]);
}

// layer 2 (final, K=128, H=64), transform-first weights
__global__ void cvt_final_w_k(const float* __restrict__ Wl, const float* __restrict__ Wr,
                              unsigned short* __restrict__ w_yu,
                              unsigned short* __restrict__ w_st,
                              unsigned short* __restrict__ wr_i,
                              unsigned short* __restrict__ wr_u) {
  int idx = blockIdx.x * blockDim.x + threadIdx.x;  // over K*H = 128*64
  if (idx >= 128 * 64) return;
  int k = idx / 64, h = idx - (idx / 64) * 64;
  int kh = 128 * 64;
  int src = k * 64 + h;
  w_yu[h * 128 + k] = f2bf(0.5f * Wl[0 * kh + src]);
  w_st[h * 128 + k] = f2bf(0.5f * Wl[2 * kh + src]);
  w_st[(h + 64) * 128 + k] = f2bf(Wl[1 * kh + src]);
  wr_i[h * 128 + k] = f2bf(0.5f * (Wr[0 * kh + src] + Wr[2 * kh + src]));
  wr_u[h * 128 + k] = f2bf(Wr[1 * kh + src]);
}

// ---------------- fused mean aggregation: sub-wave per dst node (r9) --------
// agg64: one OCTET per dst node (8 nodes/wave); agg128: one QUARTER per node.
// 4-deep unrolled gather main loop (16 row-gathers in flight per wave), no
// cross-lane reduce, direct coalesced store. Measured best (99.6us agg128);
// demand-side throughput sits at the random-256B-gather subsystem ceiling.

__global__ __launch_bounds__(256, 8) void agg64_fused_k(
    const unsigned* __restrict__ x0, int st0, int of0, const int* __restrict__ bg0,
    const int* __restrict__ en0, const unsigned* __restrict__ cl0, unsigned* __restrict__ m0,
    int nd0,
    const unsigned* __restrict__ x1, int st1, int of1, const int* __restrict__ bg1,
    const int* __restrict__ en1, const unsigned* __restrict__ cl1, unsigned* __restrict__ m1,
    int nd1,
    const unsigned* __restrict__ x2, int st2, int of2, const int* __restrict__ bg2,
    const int* __restrict__ en2, const unsigned* __restrict__ cl2, unsigned* __restrict__ m2,
    int nd2) {
  int node = blockIdx.x * 32 + (threadIdx.x >> 3);  // octet id = dst node
  int j = threadIdx.x & 7;                          // 16B chunk within 128B row
  const unsigned* xs;
  const int* bg;
  const int* en;
  const unsigned* cl;
  unsigned* mv;
  int st, ofs, wv;
  if (node < nd0) {
    xs = x0; st = st0; ofs = of0; bg = bg0; en = en0; cl = cl0; mv = m0; wv = node;
  } else if (node < nd0 + nd1) {
    xs = x1; st = st1; ofs = of1; bg = bg1; en = en1; cl = cl1; mv = m1;
    wv = node - nd0;
  } else {
    wv = node - nd0 - nd1;
    if (wv >= nd2) return;
    xs = x2; st = st2; ofs = of2; bg = bg2; en = en2; cl = cl2; mv = m2;
  }
  int b = bg[wv], ee = en[wv];
  float a[8] = {};
  int e = b;
  for (; e + 4 <= ee; e += 4) {
    int s0 = (int)cl[e];
    int s1 = (int)cl[e + 1];
    int s2 = (int)cl[e + 2];
    int s3 = (int)cl[e + 3];
    uint4 r0 = ((const uint4*)(xs + (size_t)s0 * st + ofs))[j];
    uint4 r1 = ((const uint4*)(xs + (size_t)s1 * st + ofs))[j];
    uint4 r2 = ((const uint4*)(xs + (size_t)s2 * st + ofs))[j];
    uint4 r3 = ((const uint4*)(xs + (size_t)s3 * st + ofs))[j];
    acc8(a, r0);
    acc8(a, r1);
    acc8(a, r2);
    acc8(a, r3);
  }
  for (; e < ee; ++e) {
    int s0 = (int)cl[e];
    uint4 r0 = ((const uint4*)(xs + (size_t)s0 * st + ofs))[j];
    acc8(a, r0);
  }
  float inv = 1.f / (float)max(ee - b, 1);
  ((uint4*)(mv + (size_t)wv * 32))[j] = pack8(a, inv);
}

__global__ __launch_bounds__(256, 8) void agg128_fused_k(
    const unsigned* __restrict__ x0, const int* __restrict__ bg0,
    const int* __restrict__ en0, const unsigned* __restrict__ cl0, unsigned* __restrict__ m0,
    int nd0,
    const unsigned* __restrict__ x1, const int* __restrict__ bg1,
    const int* __restrict__ en1, const unsigned* __restrict__ cl1, unsigned* __restrict__ m1,
    int nd1,
    const unsigned* __restrict__ x2, const int* __restrict__ bg2,
    const int* __restrict__ en2, const unsigned* __restrict__ cl2, unsigned* __restrict__ m2,
    int nd2) {
  int node = blockIdx.x * 16 + (threadIdx.x >> 4);  // quarter id = dst node
  int j = threadIdx.x & 15;                         // 16B chunk within 256B row
  const unsigned* xs;
  const int* bg;
  const int* en;
  const unsigned* cl;
  unsigned* mv;
  int wv;
  if (node < nd0) {
    xs = x0; bg = bg0; en = en0; cl = cl0; mv = m0; wv = node;
  } else if (node < nd0 + nd1) {
    xs = x1; bg = bg1; en = en1; cl = cl1; mv = m1; wv = node - nd0;
  } else {
    wv = node - nd0 - nd1;
    if (wv >= nd2) return;
    xs = x2; bg = bg2; en = en2; cl = cl2; mv = m2;
  }
  int b = bg[wv], ee = en[wv];
  float a[8] = {};
  int e = b;
  for (; e + 4 <= ee; e += 4) {
    int s0 = (int)cl[e];
    int s1 = (int)cl[e + 1];
    int s2 = (int)cl[e + 2];
    int s3 = (int)cl[e + 3];
    uint4 r0 = ((const uint4*)(xs + (size_t)s0 * 64))[j];
    uint4 r1 = ((const uint4*)(xs + (size_t)s1 * 64))[j];
    uint4 r2 = ((const uint4*)(xs + (size_t)s2 * 64))[j];
    uint4 r3 = ((const uint4*)(xs + (size_t)s3 * 64))[j];
    acc8(a, r0);
    acc8(a, r1);
    acc8(a, r2);
    acc8(a, r3);
  }
  for (; e < ee; ++e) {
    int s0 = (int)cl[e];
    uint4 r0 = ((const uint4*)(xs + (size_t)s0 * 64))[j];
    acc8(a, r0);
  }
  float inv = 1.f / (float)max(ee - b, 1);
  ((uint4*)(mv + (size_t)wv * 64))[j] = pack8(a, inv);
}

// ---------------- MFMA GEMM ----------------
// out = sum_ph A_ph@W_ph + bscale*(biasA[+biasB]) + add0 + add1; [relu]
// A: bf16 [n][K]; W: bf16 [H][K]; add0/1: bf16 [n][H]. fp32 acc.
// Staging via global_load_lds width-16 (m97): per wave per K-step 2 A-DMAs
// + 1 B-DMA, LDS dest linear (wave base + lane*16) matching As/Bs layout.
// OOB A-rows are clamped to n-1: they only feed output rows >= n, skipped.

__global__ __launch_bounds__(256) void gemm_mfma3_k(
    const unsigned short* __restrict__ A0, const unsigned short* __restrict__ W0,
    const unsigned short* __restrict__ A1, const unsigned short* __restrict__ W1,
    const unsigned short* __restrict__ A2, const unsigned short* __restrict__ W2,
    const float* __restrict__ biasA, const float* __restrict__ biasB, float bscale,
    const unsigned short* __restrict__ add0, const unsigned short* __restrict__ add1,
    float* __restrict__ out_f32, unsigned short* __restrict__ out_bf16, int n, int K, int H,
    int relu) {
  __shared__ alignas(16) unsigned short As[128 * 32];
  __shared__ alignas(16) unsigned short Bs[64 * 32];
  int tid = threadIdx.x;
  int row0 = blockIdx.x * 128;
  int col0 = blockIdx.y * 64;
  int w = tid >> 6, l = tid & 63;
  int lr = l & 15, lq = l >> 4;

  f32x4 acc[2][4] = {};
  int nph = A1 ? (A2 ? 3 : 2) : 1;

  for (int ph = 0; ph < nph; ++ph) {
    const unsigned short* Ap = (ph == 0) ? A0 : (ph == 1) ? A1 : A2;
    const unsigned short* Wp = (ph == 0) ? W0 : (ph == 1) ? W1 : W2;
    for (int k0 = 0; k0 < K; k0 += 32) {
      {
        // wave w stages A rows [16w,16w+16) and [16w+64,16w+80), B rows
        // [16w,16w+16). lane l -> row +(l>>2), 16B slot (l&3). LDS dest is
        // wave-uniform base + l*16 == As/Bs row-major layout exactly.
        int rr = l >> 2, cidx = l & 3;
        int agr0 = min(row0 + w * 16 + rr, n - 1);
        int agr1 = min(row0 + w * 16 + 64 + rr, n - 1);
        int bgr = col0 + w * 16 + rr;
        dma16(Ap + (size_t)agr0 * K + k0 + cidx * 8, As + (w * 16) * 32);
        dma16(Ap + (size_t)agr1 * K + k0 + cidx * 8, As + (w * 16 + 64) * 32);
        dma16(Wp + (size_t)bgr * K + k0 + cidx * 8, Bs + (w * 16) * 32);
      }
      __syncthreads();
      bf16x8 af[2], bfr[4];
#pragma unroll
      for (int t = 0; t < 2; ++t)
        af[t] = *(const bf16x8*)(As + (w * 32 + t * 16 + lr) * 32 + lq * 8);
#pragma unroll
      for (int cidx = 0; cidx < 4; ++cidx)
        bfr[cidx] = *(const bf16x8*)(Bs + (cidx * 16 + lr) * 32 + lq * 8);
#pragma unroll
      for (int t = 0; t < 2; ++t)
#pragma unroll
        for (int cidx = 0; cidx < 4; ++cidx)
          acc[t][cidx] =
              __builtin_amdgcn_mfma_f32_16x16x32_bf16(af[t], bfr[cidx], acc[t][cidx], 0, 0, 0);
      __syncthreads();
    }
  }

#pragma unroll
  for (int t = 0; t < 2; ++t) {
#pragma unroll
    for (int cidx = 0; cidx < 4; ++cidx) {
      int gc = col0 + cidx * 16 + lr;
      float b = 0.f;
      if (biasA) b = biasA[gc];
      if (biasB) b += biasB[gc];
      b *= bscale;
#pragma unroll
      for (int r = 0; r < 4; ++r) {
        int gr = row0 + w * 32 + t * 16 + lq * 4 + r;
        if (gr >= n) continue;
        float val = acc[t][cidx][r] + b;
        size_t idx = (size_t)gr * H + gc;
        if (add0) val += __uint_as_float((unsigned)add0[idx] << 16);
        if (add1) val += __uint_as_float((unsigned)add1[idx] << 16);
        if (relu) val = fmaxf(val, 0.f);
        if (out_f32) out_f32[idx] = val;
        if (out_bf16) out_bf16[idx] = f2bf(val);
      }
    }
  }
}

// ---------------------------------------------------------------------------

extern "C" void kernel_launch(void* const* d_in, const int* in_sizes, int n_in, void* d_out,
                              int out_size, void* d_ws, size_t ws_size, hipStream_t stream) {
  const int NU = 100000, NI = 30000;
  const int O = 64;
  const int SH_I = 7, SH_U = 8;        // bucket = 128 dsts (items) / 256 (users)
  const int NB_R = cdiv_i(NI, 128);    // 235
  const int NB_U = cdiv_i(NU, 256);    // 391
  const int NB_S = cdiv_i(NI, 128);    // 235
  const int CAP_R = 7424, CAP_U = 4608, CAP_S = 2688;  // mu + ~12 sigma

  const float* x_user = (const float*)d_in[0];
  const float* x_item = (const float*)d_in[1];
  const int* e_rates = (const int*)d_in[2];
  const int* e_rated = (const int*)d_in[3];
  const int* e_sim = (const int*)d_in[4];
  const int ER = in_sizes[2] / 2;
  const int ERB = in_sizes[3] / 2;
  const int ES = in_sizes[4] / 2;
  const float* Wl0 = (const float*)d_in[5];
  const float* bl0 = (const float*)d_in[6];
  const float* Wr0 = (const float*)d_in[7];
  const float* Wl1 = (const float*)d_in[8];
  const float* bl1 = (const float*)d_in[9];
  const float* Wr1 = (const float*)d_in[10];
  const float* Wl2 = (const float*)d_in[11];
  const float* bl2 = (const float*)d_in[12];
  const float* Wr2 = (const float*)d_in[13];
  float* outp = (float*)d_out;

  // ---- workspace ----
  char* wsc = (char*)d_ws;
  size_t off = 0;
  auto alloc = [&](size_t bytes) -> char* {
    size_t cur = (off + 255) & ~(size_t)255;
    off = cur + bytes;
    return wsc + cur;
  };
  typedef unsigned short u16;
  int* cnt_all = (int*)alloc((size_t)(NB_R + NB_U + NB_S) * 4);
  int* cnt_r = cnt_all;
  int* cnt_u = cnt_r + NB_R;
  int* cnt_s = cnt_u + NB_U;
  unsigned* bkt_r = (unsigned*)alloc((size_t)NB_R * CAP_R * 4);
  unsigned* bkt_u = (unsigned*)alloc((size_t)NB_U * CAP_U * 4);
  unsigned* bkt_s = (unsigned*)alloc((size_t)NB_S * CAP_S * 4);
  int* beg_r = (int*)alloc((size_t)NI * 4);
  int* end_r = (int*)alloc((size_t)NI * 4);
  int* beg_u = (int*)alloc((size_t)NU * 4);
  int* end_u = (int*)alloc((size_t)NU * 4);
  int* beg_s = (int*)alloc((size_t)NI * 4);
  int* end_s = (int*)alloc((size_t)NI * 4);
  u16* xu_bf = (u16*)alloc((size_t)(NU + 1) * 64 * 2);
  u16* xi_bf = (u16*)alloc((size_t)(NI + 1) * 64 * 2);
  u16* mi_r = (u16*)alloc((size_t)NI * 64 * 2);
  u16* mi_s = (u16*)alloc((size_t)NI * 64 * 2);
  u16* mu3 = (u16*)alloc((size_t)NU * 64 * 2);
  u16* mean_ir = (u16*)alloc((size_t)NI * 128 * 2);
  u16* mean_is = (u16*)alloc((size_t)NI * 128 * 2);
  u16* mean_u = (u16*)alloc((size_t)NU * 128 * 2);
  u16* hu_a = (u16*)alloc((size_t)(NU + 1) * 128 * 2);
  u16* hu_b = (u16*)alloc((size_t)NU * 128 * 2);
  u16* hi_a = (u16*)alloc((size_t)(NI + 1) * 128 * 2);
  u16* hi_b = (u16*)alloc((size_t)NI * 128 * 2);
  u16* yu0 = (u16*)alloc((size_t)(NU + 1) * 64 * 2);
  u16* yi_st = (u16*)alloc((size_t)(NI + 1) * 128 * 2);
  u16* w0[5];
  for (int i = 0; i < 5; ++i) w0[i] = (u16*)alloc((size_t)64 * 128 * 2);
  u16* w1[5];
  for (int i = 0; i < 5; ++i) w1[i] = (u16*)alloc((size_t)128 * 128 * 2);
  u16* w2_yu = (u16*)alloc((size_t)64 * 128 * 2);
  u16* w2_st = (u16*)alloc((size_t)128 * 128 * 2);
  u16* wr_i2 = (u16*)alloc((size_t)64 * 128 * 2);
  u16* wr_u2 = (u16*)alloc((size_t)64 * 128 * 2);
  (void)ws_size;

  // ---- build + sort ----
  hipMemsetAsync(cnt_all, 0, (size_t)(NB_R + NB_U + NB_S) * 4, stream);
  int NC_R = cdiv_i(ER, CHUNK), NC_U = cdiv_i(ERB, CHUNK), NC_S = cdiv_i(ES, CHUNK);
  build_buckets_k<<<NC_R + NC_U + NC_S, 1024, 0, stream>>>(
      e_rates, e_rates + ER, ER, NC_R, NB_R, SH_I, CAP_R, cnt_r, bkt_r,
      e_rated, e_rated + ERB, ERB, NC_U, NB_U, SH_U, CAP_U, cnt_u, bkt_u,
      e_sim, e_sim + ES, ES, NC_S, NB_S, SH_I, CAP_S, cnt_s, bkt_s);
  sort_bucket_k<<<NB_R + NB_U + NB_S, 512, (size_t)CAP_R * 4, stream>>>(
      bkt_r, cnt_r, NB_R, SH_I, CAP_R, beg_r, end_r, NI,
      bkt_u, cnt_u, NB_U, SH_U, CAP_U, beg_u, end_u, NU,
      bkt_s, cnt_s, NB_S, SH_I, CAP_S, beg_s, end_s, NI);

  // ---- conversions ----
  cvt_f32_bf16_k<<<cdiv_i(NU * 64 / 4, 256), 256, 0, stream>>>(x_user, xu_bf, NU * 64 / 4);
  cvt_f32_bf16_k<<<cdiv_i(NI * 64 / 4, 256), 256, 0, stream>>>(x_item, xi_bf, NI * 64 / 4);
  cvt_layer_w_k<<<cdiv_i(64 * 128, 256), 256, 0, stream>>>(Wl0, Wr0, 64, 128, w0[0], w0[1],
                                                           w0[2], w0[3], w0[4]);
  cvt_layer_w_k<<<cdiv_i(128 * 128, 256), 256, 0, stream>>>(Wl1, Wr1, 128, 128, w1[0], w1[1],
                                                            w1[2], w1[3], w1[4]);
  cvt_final_w_k<<<cdiv_i(128 * 64, 256), 256, 0, stream>>>(Wl2, Wr2, w2_yu, w2_st, wr_i2,
                                                           wr_u2);

  // ---- layer 1 (K=64 -> H=128) ----
  {
    agg64_fused_k<<<cdiv_i(NI + NI + NU, 32), 256, 0, stream>>>(
        (const unsigned*)xu_bf, 32, 0, beg_r, end_r, bkt_r, (unsigned*)mi_r, NI,
        (const unsigned*)xi_bf, 32, 0, beg_s, end_s, bkt_s, (unsigned*)mi_s, NI,
        (const unsigned*)xi_bf, 32, 0, beg_u, end_u, bkt_u, (unsigned*)mu3, NU);
    dim3 gi(cdiv_i(NI, 128), 2), gu(cdiv_i(NU, 128), 2);
    gemm_mfma3_k<<<gi, 256, 0, stream>>>(mi_r, w0[0], mi_s, w0[1], xi_bf, w0[2], bl0 + 0 * 128,
                                         bl0 + 2 * 128, 0.5f, nullptr, nullptr, nullptr, hi_a,
                                         NI, 64, 128, 1);
    gemm_mfma3_k<<<gu, 256, 0, stream>>>(mu3, w0[3], xu_bf, w0[4], nullptr, nullptr,
                                         bl0 + 1 * 128, nullptr, 1.0f, nullptr, nullptr,
                                         nullptr, hu_a, NU, 64, 128, 1);
  }
  // ---- layer 2 (K=128 -> H=128) ----
  {
    agg128_fused_k<<<cdiv_i(NI + NI + NU, 16), 256, 0, stream>>>(
        (const unsigned*)hu_a, beg_r, end_r, bkt_r, (unsigned*)mean_ir, NI,
        (const unsigned*)hi_a, beg_s, end_s, bkt_s, (unsigned*)mean_is, NI,
        (const unsigned*)hi_a, beg_u, end_u, bkt_u, (unsigned*)mean_u, NU);
    dim3 gi(cdiv_i(NI, 128), 2), gu(cdiv_i(NU, 128), 2);
    gemm_mfma3_k<<<gi, 256, 0, stream>>>(mean_ir, w1[0], mean_is, w1[1], hi_a, w1[2],
                                         bl1 + 0 * 128, bl1 + 2 * 128, 0.5f, nullptr, nullptr,
                                         nullptr, hi_b, NI, 128, 128, 1);
    gemm_mfma3_k<<<gu, 256, 0, stream>>>(mean_u, w1[3], hu_a, w1[4], nullptr, nullptr,
                                         bl1 + 1 * 128, nullptr, 1.0f, nullptr, nullptr,
                                         nullptr, hu_b, NU, 128, 128, 1);
  }
  // ---- layer 3 (K=128 -> O=64), transform-first ----
  {
    dim3 gp1(cdiv_i(NU, 128), 1), gp2(cdiv_i(NI, 128), 2);
    gemm_mfma3_k<<<gp1, 256, 0, stream>>>(hu_b, w2_yu, nullptr, nullptr, nullptr, nullptr,
                                          nullptr, nullptr, 0.f, nullptr, nullptr, nullptr,
                                          yu0, NU, 128, 64, 0);
    gemm_mfma3_k<<<gp2, 256, 0, stream>>>(hi_b, w2_st, nullptr, nullptr, nullptr, nullptr,
                                          nullptr, nullptr, 0.f, nullptr, nullptr, nullptr,
                                          yi_st, NI, 128, 128, 0);
    agg64_fused_k<<<cdiv_i(NI + NI + NU, 32), 256, 0, stream>>>(
        (const unsigned*)yu0, 32, 0, beg_r, end_r, bkt_r, (unsigned*)mi_r, NI,
        (const unsigned*)yi_st, 64, 0, beg_s, end_s, bkt_s, (unsigned*)mi_s, NI,
        (const unsigned*)yi_st, 64, 32, beg_u, end_u, bkt_u, (unsigned*)mu3, NU);
    dim3 gi(cdiv_i(NI, 128), 1), gu(cdiv_i(NU, 128), 1);
    gemm_mfma3_k<<<gi, 256, 0, stream>>>(hi_b, wr_i2, nullptr, nullptr, nullptr, nullptr,
                                         bl2 + 0 * 64, bl2 + 2 * 64, 0.5f, mi_r, mi_s,
                                         outp + (size_t)NU * O, nullptr, NI, 128, 64, 0);
    gemm_mfma3_k<<<gu, 256, 0, stream>>>(hu_b, wr_u2, nullptr, nullptr, nullptr, nullptr,
                                         bl2 + 1 * 64, nullptr, 1.0f, mu3, nullptr, outp,
                                         nullptr, NU, 128, 64, 0);
  }
}